// Round 1
// baseline (1354.925 us; speedup 1.0000x reference)
//
#include <hip/hip_runtime.h>
#include <hip/hip_bf16.h>

#define B_  2
#define N_  2048
#define E_  1024
#define H_  16
#define HD_ 64
#define M_  (B_*N_)

__device__ __forceinline__ float bf2f(unsigned short u) {
    return __uint_as_float(((unsigned)u) << 16);
}
__device__ __forceinline__ unsigned short f2bfu(float f) {
    __hip_bfloat16 h = __float2bfloat16(f);
    return *reinterpret_cast<unsigned short*>(&h);
}

// ---------------------------------------------------------------------------
// Kernel 1: QKV projection.  y = x @ W^T (both row-major, K contiguous -> NT)
// Writes bf16 into ws in [B][H][N][64] layout; Q pre-scaled by 1/sqrt(64).
// ---------------------------------------------------------------------------
__global__ __launch_bounds__(256) void qkv_gemm_kernel(
    const float* __restrict__ x, const float* __restrict__ Wq,
    const float* __restrict__ Wk, const float* __restrict__ Wv,
    unsigned short* __restrict__ qkv)
{
    const int z = blockIdx.z;
    const float* __restrict__ W = (z == 0) ? Wq : (z == 1 ? Wk : Wv);
    unsigned short* __restrict__ out = qkv + (size_t)z * M_ * E_;
    const int m0 = blockIdx.y * 64;
    const int n0 = blockIdx.x * 64;
    __shared__ float Xs[64][65];
    __shared__ float Ws_[64][65];
    const int t = threadIdx.x;
    const int tx = t & 15, ty = t >> 4;
    float acc[4][4] = {{0.f}};
    for (int k0 = 0; k0 < E_; k0 += 64) {
        #pragma unroll
        for (int i = 0; i < 4; ++i) {
            const int r = i * 16 + ty;
            const int c = tx * 4;
            const float4 xv = *reinterpret_cast<const float4*>(x + (size_t)(m0 + r) * E_ + k0 + c);
            Xs[r][c+0] = xv.x; Xs[r][c+1] = xv.y; Xs[r][c+2] = xv.z; Xs[r][c+3] = xv.w;
            const float4 wv = *reinterpret_cast<const float4*>(W + (size_t)(n0 + r) * E_ + k0 + c);
            Ws_[r][c+0] = wv.x; Ws_[r][c+1] = wv.y; Ws_[r][c+2] = wv.z; Ws_[r][c+3] = wv.w;
        }
        __syncthreads();
        #pragma unroll 8
        for (int kk = 0; kk < 64; ++kk) {
            float a[4], b[4];
            #pragma unroll
            for (int i = 0; i < 4; ++i) a[i] = Xs[ty*4 + i][kk];
            #pragma unroll
            for (int j = 0; j < 4; ++j) b[j] = Ws_[tx*4 + j][kk];
            #pragma unroll
            for (int i = 0; i < 4; ++i)
                #pragma unroll
                for (int j = 0; j < 4; ++j)
                    acc[i][j] = fmaf(a[i], b[j], acc[i][j]);
        }
        __syncthreads();
    }
    const float scale = (z == 0) ? 0.125f : 1.0f;
    #pragma unroll
    for (int i = 0; i < 4; ++i) {
        const int m = m0 + ty*4 + i;
        const int b = m >> 11;            // N_ = 2048 = 2^11
        const int npos = m & (N_ - 1);
        #pragma unroll
        for (int j = 0; j < 4; ++j) {
            const int n = n0 + tx*4 + j;
            const int h = n >> 6, d = n & 63;
            out[(((size_t)(b * H_ + h)) * N_ + npos) * HD_ + d] = f2bfu(acc[i][j] * scale);
        }
    }
}

// ---------------------------------------------------------------------------
// Kernel 2: flash attention. Block = 256 threads handles 64 q-rows of one
// (b,h). Online softmax, causal mask. Q/K/V bf16 in ws, compute fp32.
// ---------------------------------------------------------------------------
__global__ __launch_bounds__(256) void attn_kernel(
    const unsigned short* __restrict__ ws, unsigned short* __restrict__ attn_out)
{
    const int qt = blockIdx.x;      // q tile 0..31
    const int bh = blockIdx.y;      // 0..31
    const int q0 = qt * 64;
    const unsigned short* Qp = ws + (size_t)bh * N_ * HD_;
    const unsigned short* Kp = ws + (size_t)M_ * E_ + (size_t)bh * N_ * HD_;
    const unsigned short* Vp = ws + 2 * (size_t)M_ * E_ + (size_t)bh * N_ * HD_;
    __shared__ float Qs[64][65], Ks[64][65], Vs[64][65], Ps[64][65];
    __shared__ float red[64][16];
    __shared__ float mrow[64], lrow[64], srow[64];
    const int t = threadIdx.x;
    const int tx = t & 15, ty = t >> 4;

    #pragma unroll
    for (int i = 0; i < 4; ++i) {
        const int r = i * 16 + ty, c = tx * 4;
        const ushort4 q4 = *reinterpret_cast<const ushort4*>(Qp + (size_t)(q0 + r) * HD_ + c);
        Qs[r][c+0] = bf2f(q4.x); Qs[r][c+1] = bf2f(q4.y);
        Qs[r][c+2] = bf2f(q4.z); Qs[r][c+3] = bf2f(q4.w);
    }
    if (t < 64) { mrow[t] = -1e30f; lrow[t] = 0.f; }
    float O[4][4] = {{0.f}};

    for (int kt = 0; kt <= qt; ++kt) {
        const int k0 = kt * 64;
        __syncthreads();   // protect Ks/Vs (prev PV) and cover Qs/mrow init
        #pragma unroll
        for (int i = 0; i < 4; ++i) {
            const int r = i * 16 + ty, c = tx * 4;
            const ushort4 k4 = *reinterpret_cast<const ushort4*>(Kp + (size_t)(k0 + r) * HD_ + c);
            Ks[r][c+0] = bf2f(k4.x); Ks[r][c+1] = bf2f(k4.y);
            Ks[r][c+2] = bf2f(k4.z); Ks[r][c+3] = bf2f(k4.w);
            const ushort4 v4 = *reinterpret_cast<const ushort4*>(Vp + (size_t)(k0 + r) * HD_ + c);
            Vs[r][c+0] = bf2f(v4.x); Vs[r][c+1] = bf2f(v4.y);
            Vs[r][c+2] = bf2f(v4.z); Vs[r][c+3] = bf2f(v4.w);
        }
        __syncthreads();

        // scores S = Q K^T (Q already scaled)
        float s[4][4] = {{0.f}};
        #pragma unroll 8
        for (int kk = 0; kk < 64; ++kk) {
            float a[4], b[4];
            #pragma unroll
            for (int i = 0; i < 4; ++i) a[i] = Qs[ty*4 + i][kk];
            #pragma unroll
            for (int j = 0; j < 4; ++j) b[j] = Ks[tx*4 + j][kk];
            #pragma unroll
            for (int i = 0; i < 4; ++i)
                #pragma unroll
                for (int j = 0; j < 4; ++j)
                    s[i][j] = fmaf(a[i], b[j], s[i][j]);
        }
        if (kt == qt) {
            #pragma unroll
            for (int i = 0; i < 4; ++i)
                #pragma unroll
                for (int j = 0; j < 4; ++j)
                    if (k0 + tx*4 + j > q0 + ty*4 + i) s[i][j] = -1e30f;
        }

        // row max reduce
        #pragma unroll
        for (int i = 0; i < 4; ++i) {
            float tm = fmaxf(fmaxf(s[i][0], s[i][1]), fmaxf(s[i][2], s[i][3]));
            red[ty*4 + i][tx] = tm;
        }
        __syncthreads();
        if (t < 64) {
            float mt = red[t][0];
            #pragma unroll
            for (int c = 1; c < 16; ++c) mt = fmaxf(mt, red[t][c]);
            const float mnew = fmaxf(mrow[t], mt);
            srow[t] = __expf(mrow[t] - mnew);
            mrow[t] = mnew;
        }
        __syncthreads();

        // probs + row sum
        float tsum[4] = {0.f, 0.f, 0.f, 0.f};
        #pragma unroll
        for (int i = 0; i < 4; ++i) {
            const float mr = mrow[ty*4 + i];
            #pragma unroll
            for (int j = 0; j < 4; ++j) {
                const float p = __expf(s[i][j] - mr);
                Ps[ty*4 + i][tx*4 + j] = p;
                tsum[i] += p;
            }
        }
        #pragma unroll
        for (int i = 0; i < 4; ++i) red[ty*4 + i][tx] = tsum[i];
        __syncthreads();
        if (t < 64) {
            float ssum = 0.f;
            #pragma unroll
            for (int c = 0; c < 16; ++c) ssum += red[t][c];
            lrow[t] = lrow[t] * srow[t] + ssum;
        }

        // O rescale + PV
        #pragma unroll
        for (int i = 0; i < 4; ++i) {
            const float sc = srow[ty*4 + i];
            #pragma unroll
            for (int j = 0; j < 4; ++j) O[i][j] *= sc;
        }
        #pragma unroll 8
        for (int kk = 0; kk < 64; ++kk) {
            float a[4], b[4];
            #pragma unroll
            for (int i = 0; i < 4; ++i) a[i] = Ps[ty*4 + i][kk];
            #pragma unroll
            for (int j = 0; j < 4; ++j) b[j] = Vs[kk][tx*4 + j];
            #pragma unroll
            for (int i = 0; i < 4; ++i)
                #pragma unroll
                for (int j = 0; j < 4; ++j)
                    O[i][j] = fmaf(a[i], b[j], O[i][j]);
        }
    }
    __syncthreads();   // lrow final visible to all

    const int b = bh >> 4, h = bh & 15;
    #pragma unroll
    for (int i = 0; i < 4; ++i) {
        const int q = q0 + ty*4 + i;
        const float inv = 1.0f / lrow[ty*4 + i];
        #pragma unroll
        for (int j = 0; j < 4; ++j) {
            const int e = h * HD_ + tx*4 + j;
            attn_out[((size_t)(b * N_ + q)) * E_ + e] = f2bfu(O[i][j] * inv);
        }
    }
}

// ---------------------------------------------------------------------------
// Kernel 3: out = attn @ Wo^T + bo   (A bf16, Wo fp32, out fp32)
// ---------------------------------------------------------------------------
__global__ __launch_bounds__(256) void out_gemm_kernel(
    const unsigned short* __restrict__ A, const float* __restrict__ Wo,
    const float* __restrict__ bo, float* __restrict__ out)
{
    const int m0 = blockIdx.y * 64;
    const int n0 = blockIdx.x * 64;
    __shared__ float As[64][65];
    __shared__ float Ws_[64][65];
    const int t = threadIdx.x;
    const int tx = t & 15, ty = t >> 4;
    float acc[4][4] = {{0.f}};
    for (int k0 = 0; k0 < E_; k0 += 64) {
        #pragma unroll
        for (int i = 0; i < 4; ++i) {
            const int r = i * 16 + ty;
            const int c = tx * 4;
            const ushort4 a4 = *reinterpret_cast<const ushort4*>(A + (size_t)(m0 + r) * E_ + k0 + c);
            As[r][c+0] = bf2f(a4.x); As[r][c+1] = bf2f(a4.y);
            As[r][c+2] = bf2f(a4.z); As[r][c+3] = bf2f(a4.w);
            const float4 wv = *reinterpret_cast<const float4*>(Wo + (size_t)(n0 + r) * E_ + k0 + c);
            Ws_[r][c+0] = wv.x; Ws_[r][c+1] = wv.y; Ws_[r][c+2] = wv.z; Ws_[r][c+3] = wv.w;
        }
        __syncthreads();
        #pragma unroll 8
        for (int kk = 0; kk < 64; ++kk) {
            float a[4], b[4];
            #pragma unroll
            for (int i = 0; i < 4; ++i) a[i] = As[ty*4 + i][kk];
            #pragma unroll
            for (int j = 0; j < 4; ++j) b[j] = Ws_[tx*4 + j][kk];
            #pragma unroll
            for (int i = 0; i < 4; ++i)
                #pragma unroll
                for (int j = 0; j < 4; ++j)
                    acc[i][j] = fmaf(a[i], b[j], acc[i][j]);
        }
        __syncthreads();
    }
    #pragma unroll
    for (int i = 0; i < 4; ++i) {
        const int m = m0 + ty*4 + i;
        #pragma unroll
        for (int j = 0; j < 4; ++j) {
            const int n = n0 + tx*4 + j;
            out[(size_t)m * E_ + n] = acc[i][j] + bo[n];
        }
    }
}

extern "C" void kernel_launch(void* const* d_in, const int* in_sizes, int n_in,
                              void* d_out, int out_size, void* d_ws, size_t ws_size,
                              hipStream_t stream) {
    const float* x  = (const float*)d_in[0];
    // d_in[1] = mask (causal tril, applied analytically)
    const float* Wq = (const float*)d_in[2];
    const float* Wk = (const float*)d_in[3];
    const float* Wv = (const float*)d_in[4];
    const float* Wo = (const float*)d_in[5];
    const float* bo = (const float*)d_in[6];
    float* out = (float*)d_out;

    unsigned short* ws = (unsigned short*)d_ws;           // bf16 Q|K|V|attn
    unsigned short* attn_ws = ws + 3 * (size_t)M_ * E_;

    dim3 g1(E_ / 64, M_ / 64, 3);
    qkv_gemm_kernel<<<g1, 256, 0, stream>>>(x, Wq, Wk, Wv, ws);

    dim3 g2(N_ / 64, B_ * H_);
    attn_kernel<<<g2, 256, 0, stream>>>(ws, attn_ws);

    dim3 g3(E_ / 64, M_ / 64);
    out_gemm_kernel<<<g3, 256, 0, stream>>>(attn_ws, Wo, bo, out);
}

// Round 2
// 301.635 us; speedup vs baseline: 4.4919x; 4.4919x over previous
//
#include <hip/hip_runtime.h>
#include <hip/hip_bf16.h>

#define B_  2
#define N_  2048
#define E_  1024
#define H_  16
#define HD_ 64
#define M_  (B_*N_)

typedef short bf16x8 __attribute__((ext_vector_type(8)));
typedef float f32x4 __attribute__((ext_vector_type(4)));
typedef unsigned short u16x8 __attribute__((ext_vector_type(8)));

__device__ __forceinline__ unsigned short f2bfu(float f) {
    __hip_bfloat16 h = __float2bfloat16(f);
    return *reinterpret_cast<unsigned short*>(&h);
}
#define MFMA16(a,b,c) __builtin_amdgcn_mfma_f32_16x16x32_bf16((a),(b),(c),0,0,0)

// ---------------------------------------------------------------------------
// Kernel 1: QKV projection via MFMA.  y = x @ W^T  (NT, K contiguous both)
// 128x128 tile, 4 waves each 64x64. fp32 inputs converted to bf16 at staging.
// Writes bf16 [B][H][N][64]; Q pre-scaled by 1/8.
// ---------------------------------------------------------------------------
__global__ __launch_bounds__(256) void qkv_mfma_kernel(
    const float* __restrict__ x, const float* __restrict__ Wq,
    const float* __restrict__ Wk, const float* __restrict__ Wv,
    unsigned short* __restrict__ qkv)
{
    const int z = blockIdx.z;
    const float* __restrict__ W = (z == 0) ? Wq : (z == 1 ? Wk : Wv);
    unsigned short* __restrict__ out = qkv + (size_t)z * M_ * E_;
    const int m0 = blockIdx.y * 128;
    const int n0 = blockIdx.x * 128;
    __shared__ unsigned short As[128][72];   // stride 144B: 16B aligned, 2-way banks
    __shared__ unsigned short Bs[128][72];
    const int t = threadIdx.x;
    const int lane = t & 63;
    const int w = t >> 6, wr = w >> 1, wc = w & 1;
    const int fr = lane & 15, fq = lane >> 4;
    const int srow = t >> 1, scol = (t & 1) * 32;
    f32x4 acc[4][4] = {};

    for (int k0 = 0; k0 < E_; k0 += 64) {
        float4 a4[8], b4[8];
        const float4* ap = reinterpret_cast<const float4*>(x + (size_t)(m0 + srow) * E_ + k0 + scol);
        const float4* bp = reinterpret_cast<const float4*>(W + (size_t)(n0 + srow) * E_ + k0 + scol);
        #pragma unroll
        for (int i = 0; i < 8; ++i) a4[i] = ap[i];
        #pragma unroll
        for (int i = 0; i < 8; ++i) b4[i] = bp[i];
        __syncthreads();   // prev iter's ds_reads done before overwrite
        #pragma unroll
        for (int j = 0; j < 4; ++j) {
            u16x8 va, vb;
            va[0]=f2bfu(a4[2*j].x); va[1]=f2bfu(a4[2*j].y); va[2]=f2bfu(a4[2*j].z); va[3]=f2bfu(a4[2*j].w);
            va[4]=f2bfu(a4[2*j+1].x); va[5]=f2bfu(a4[2*j+1].y); va[6]=f2bfu(a4[2*j+1].z); va[7]=f2bfu(a4[2*j+1].w);
            vb[0]=f2bfu(b4[2*j].x); vb[1]=f2bfu(b4[2*j].y); vb[2]=f2bfu(b4[2*j].z); vb[3]=f2bfu(b4[2*j].w);
            vb[4]=f2bfu(b4[2*j+1].x); vb[5]=f2bfu(b4[2*j+1].y); vb[6]=f2bfu(b4[2*j+1].z); vb[7]=f2bfu(b4[2*j+1].w);
            *reinterpret_cast<u16x8*>(&As[srow][scol + 8*j]) = va;
            *reinterpret_cast<u16x8*>(&Bs[srow][scol + 8*j]) = vb;
        }
        __syncthreads();
        #pragma unroll
        for (int ks = 0; ks < 2; ++ks) {
            bf16x8 af[4], bfv[4];
            #pragma unroll
            for (int mf = 0; mf < 4; ++mf)
                af[mf] = *reinterpret_cast<const bf16x8*>(&As[wr*64 + mf*16 + fr][ks*32 + fq*8]);
            #pragma unroll
            for (int nf = 0; nf < 4; ++nf)
                bfv[nf] = *reinterpret_cast<const bf16x8*>(&Bs[wc*64 + nf*16 + fr][ks*32 + fq*8]);
            #pragma unroll
            for (int mf = 0; mf < 4; ++mf)
                #pragma unroll
                for (int nf = 0; nf < 4; ++nf)
                    acc[mf][nf] = MFMA16(af[mf], bfv[nf], acc[mf][nf]);
        }
    }

    const float scale = (z == 0) ? 0.125f : 1.0f;
    #pragma unroll
    for (int mf = 0; mf < 4; ++mf) {
        #pragma unroll
        for (int r = 0; r < 4; ++r) {
            const int m = m0 + wr*64 + mf*16 + fq*4 + r;
            const int b = m >> 11, npos = m & (N_ - 1);
            #pragma unroll
            for (int nf = 0; nf < 4; ++nf) {
                const int n = n0 + wc*64 + nf*16 + fr;
                const int h = n >> 6, d = n & 63;
                out[(((size_t)(b*H_ + h))*N_ + npos)*HD_ + d] = f2bfu(acc[mf][nf][r] * scale);
            }
        }
    }
}

// ---------------------------------------------------------------------------
// Kernel 2: MFMA flash attention. 4 waves / block, 64 q-rows of one (b,h).
// Wave w owns q-rows [w*16, w*16+16). K row-major in LDS (= B-operand of
// QK^T directly); V transposed at stage time so PV B-frag is ds_read_b128.
// P goes through LDS as bf16 (wave-private rows -> no barrier needed).
// ---------------------------------------------------------------------------
__global__ __launch_bounds__(256) void attn_mfma_kernel(
    const unsigned short* __restrict__ ws, unsigned short* __restrict__ attn_out)
{
    const int qt = blockIdx.x;      // 0..31
    const int bh = blockIdx.y;      // 0..31
    const int q0 = qt * 64;
    const unsigned short* Qp = ws + (size_t)bh * N_ * HD_;
    const unsigned short* Kp = ws + (size_t)M_ * E_ + (size_t)bh * N_ * HD_;
    const unsigned short* Vp = ws + 2*(size_t)M_ * E_ + (size_t)bh * N_ * HD_;
    __shared__ unsigned short Qs[64][72], Ks[64][72], Vt[64][72], Ps[64][72];
    const int t = threadIdx.x;
    const int lane = t & 63, w = t >> 6;
    const int fr = lane & 15, fq = lane >> 4;
    const int srow = t >> 2, sd0 = (t & 3) * 16;

    {   // stage Q once (already scaled by 1/8)
        const u16x8* src = reinterpret_cast<const u16x8*>(Qp + (size_t)(q0 + srow) * HD_ + sd0);
        *reinterpret_cast<u16x8*>(&Qs[srow][sd0])     = src[0];
        *reinterpret_cast<u16x8*>(&Qs[srow][sd0 + 8]) = src[1];
    }
    float m_run[4] = {-1e30f,-1e30f,-1e30f,-1e30f};
    float l_run[4] = {0.f,0.f,0.f,0.f};
    f32x4 o[4] = {};

    for (int kt = 0; kt <= qt; ++kt) {
        const int k0 = kt * 64;
        __syncthreads();   // prev PV done; also covers Q staging at kt==0
        {
            const u16x8* ksrc = reinterpret_cast<const u16x8*>(Kp + (size_t)(k0 + srow) * HD_ + sd0);
            const u16x8* vsrc = reinterpret_cast<const u16x8*>(Vp + (size_t)(k0 + srow) * HD_ + sd0);
            u16x8 k0v = ksrc[0], k1v = ksrc[1];
            u16x8 v0v = vsrc[0], v1v = vsrc[1];
            *reinterpret_cast<u16x8*>(&Ks[srow][sd0])     = k0v;
            *reinterpret_cast<u16x8*>(&Ks[srow][sd0 + 8]) = k1v;
            #pragma unroll
            for (int j = 0; j < 8; ++j) {
                Vt[sd0 + j][srow]     = v0v[j];
                Vt[sd0 + 8 + j][srow] = v1v[j];
            }
        }
        __syncthreads();

        // S = Q K^T  (wave's 16 q-rows x 64 k-cols)
        f32x4 s[4] = {};
        #pragma unroll
        for (int ks = 0; ks < 2; ++ks) {
            bf16x8 aq = *reinterpret_cast<const bf16x8*>(&Qs[w*16 + fr][ks*32 + fq*8]);
            #pragma unroll
            for (int nf = 0; nf < 4; ++nf) {
                bf16x8 bk = *reinterpret_cast<const bf16x8*>(&Ks[nf*16 + fr][ks*32 + fq*8]);
                s[nf] = MFMA16(aq, bk, s[nf]);
            }
        }
        if (kt == qt) {     // causal mask on diagonal tile
            #pragma unroll
            for (int nf = 0; nf < 4; ++nf)
                #pragma unroll
                for (int r = 0; r < 4; ++r) {
                    const int ql = w*16 + fq*4 + r, kl = nf*16 + fr;
                    if (kl > ql) s[nf][r] = -1e30f;
                }
        }

        // online softmax, fully wave-parallel (rows live in 16-lane groups)
        float scale_[4], rs[4];
        #pragma unroll
        for (int r = 0; r < 4; ++r) {
            float pm = fmaxf(fmaxf(s[0][r], s[1][r]), fmaxf(s[2][r], s[3][r]));
            pm = fmaxf(pm, __shfl_xor(pm, 1));
            pm = fmaxf(pm, __shfl_xor(pm, 2));
            pm = fmaxf(pm, __shfl_xor(pm, 4));
            pm = fmaxf(pm, __shfl_xor(pm, 8));
            const float mnew = fmaxf(m_run[r], pm);
            scale_[r] = __expf(m_run[r] - mnew);
            m_run[r] = mnew;
            rs[r] = 0.f;
        }
        #pragma unroll
        for (int nf = 0; nf < 4; ++nf)
            #pragma unroll
            for (int r = 0; r < 4; ++r) {
                const float p = __expf(s[nf][r] - m_run[r]);
                rs[r] += p;
                Ps[w*16 + fq*4 + r][nf*16 + fr] = f2bfu(p);
            }
        #pragma unroll
        for (int r = 0; r < 4; ++r) {
            float v = rs[r];
            v += __shfl_xor(v, 1);
            v += __shfl_xor(v, 2);
            v += __shfl_xor(v, 4);
            v += __shfl_xor(v, 8);
            l_run[r] = l_run[r] * scale_[r] + v;
        }
        #pragma unroll
        for (int df = 0; df < 4; ++df)
            #pragma unroll
            for (int r = 0; r < 4; ++r)
                o[df][r] *= scale_[r];

        // O += P V   (Ps rows are wave-private; same-wave ds_write->ds_read)
        #pragma unroll
        for (int ks = 0; ks < 2; ++ks) {
            bf16x8 apv = *reinterpret_cast<const bf16x8*>(&Ps[w*16 + fr][ks*32 + fq*8]);
            #pragma unroll
            for (int df = 0; df < 4; ++df) {
                bf16x8 bv = *reinterpret_cast<const bf16x8*>(&Vt[df*16 + fr][ks*32 + fq*8]);
                o[df] = MFMA16(apv, bv, o[df]);
            }
        }
    }

    const int b = bh >> 4, h = bh & 15;
    #pragma unroll
    for (int r = 0; r < 4; ++r) {
        const int q = q0 + w*16 + fq*4 + r;
        const float inv = 1.0f / l_run[r];
        #pragma unroll
        for (int df = 0; df < 4; ++df)
            attn_out[((size_t)(b*N_ + q))*E_ + h*64 + df*16 + fr] = f2bfu(o[df][r] * inv);
    }
}

// ---------------------------------------------------------------------------
// Kernel 3: out = attn @ Wo^T + bo  (A bf16, Wo fp32->bf16, out fp32), MFMA.
// ---------------------------------------------------------------------------
__global__ __launch_bounds__(256) void out_mfma_kernel(
    const unsigned short* __restrict__ A, const float* __restrict__ Wo,
    const float* __restrict__ bo, float* __restrict__ out)
{
    const int m0 = blockIdx.y * 128;
    const int n0 = blockIdx.x * 128;
    __shared__ unsigned short As[128][72];
    __shared__ unsigned short Bs[128][72];
    const int t = threadIdx.x;
    const int lane = t & 63;
    const int w = t >> 6, wr = w >> 1, wc = w & 1;
    const int fr = lane & 15, fq = lane >> 4;
    const int srow = t >> 1, scol = (t & 1) * 32;
    f32x4 acc[4][4] = {};

    for (int k0 = 0; k0 < E_; k0 += 64) {
        u16x8 a8[4];
        float4 b4[8];
        const u16x8* ap = reinterpret_cast<const u16x8*>(A + (size_t)(m0 + srow) * E_ + k0 + scol);
        const float4* bp = reinterpret_cast<const float4*>(Wo + (size_t)(n0 + srow) * E_ + k0 + scol);
        #pragma unroll
        for (int i = 0; i < 4; ++i) a8[i] = ap[i];
        #pragma unroll
        for (int i = 0; i < 8; ++i) b4[i] = bp[i];
        __syncthreads();
        #pragma unroll
        for (int j = 0; j < 4; ++j) {
            u16x8 vb;
            vb[0]=f2bfu(b4[2*j].x); vb[1]=f2bfu(b4[2*j].y); vb[2]=f2bfu(b4[2*j].z); vb[3]=f2bfu(b4[2*j].w);
            vb[4]=f2bfu(b4[2*j+1].x); vb[5]=f2bfu(b4[2*j+1].y); vb[6]=f2bfu(b4[2*j+1].z); vb[7]=f2bfu(b4[2*j+1].w);
            *reinterpret_cast<u16x8*>(&As[srow][scol + 8*j]) = a8[j];
            *reinterpret_cast<u16x8*>(&Bs[srow][scol + 8*j]) = vb;
        }
        __syncthreads();
        #pragma unroll
        for (int ks = 0; ks < 2; ++ks) {
            bf16x8 af[4], bfv[4];
            #pragma unroll
            for (int mf = 0; mf < 4; ++mf)
                af[mf] = *reinterpret_cast<const bf16x8*>(&As[wr*64 + mf*16 + fr][ks*32 + fq*8]);
            #pragma unroll
            for (int nf = 0; nf < 4; ++nf)
                bfv[nf] = *reinterpret_cast<const bf16x8*>(&Bs[wc*64 + nf*16 + fr][ks*32 + fq*8]);
            #pragma unroll
            for (int mf = 0; mf < 4; ++mf)
                #pragma unroll
                for (int nf = 0; nf < 4; ++nf)
                    acc[mf][nf] = MFMA16(af[mf], bfv[nf], acc[mf][nf]);
        }
    }

    #pragma unroll
    for (int mf = 0; mf < 4; ++mf) {
        #pragma unroll
        for (int r = 0; r < 4; ++r) {
            const int m = m0 + wr*64 + mf*16 + fq*4 + r;
            #pragma unroll
            for (int nf = 0; nf < 4; ++nf) {
                const int n = n0 + wc*64 + nf*16 + fr;
                out[(size_t)m * E_ + n] = acc[mf][nf][r] + bo[n];
            }
        }
    }
}

extern "C" void kernel_launch(void* const* d_in, const int* in_sizes, int n_in,
                              void* d_out, int out_size, void* d_ws, size_t ws_size,
                              hipStream_t stream) {
    const float* x  = (const float*)d_in[0];
    // d_in[1] = mask (causal tril, applied analytically)
    const float* Wq = (const float*)d_in[2];
    const float* Wk = (const float*)d_in[3];
    const float* Wv = (const float*)d_in[4];
    const float* Wo = (const float*)d_in[5];
    const float* bo = (const float*)d_in[6];
    float* out = (float*)d_out;

    unsigned short* ws = (unsigned short*)d_ws;           // bf16 Q|K|V|attn
    unsigned short* attn_ws = ws + 3 * (size_t)M_ * E_;

    dim3 g1(E_ / 128, M_ / 128, 3);
    qkv_mfma_kernel<<<g1, 256, 0, stream>>>(x, Wq, Wk, Wv, ws);

    dim3 g2(N_ / 64, B_ * H_);
    attn_mfma_kernel<<<g2, 256, 0, stream>>>(ws, attn_ws);

    dim3 g3(E_ / 128, M_ / 128);
    out_mfma_kernel<<<g3, 256, 0, stream>>>(attn_ws, Wo, bo, out);
}

// Round 3
// 245.896 us; speedup vs baseline: 5.5102x; 1.2267x over previous
//
#include <hip/hip_runtime.h>
#include <hip/hip_bf16.h>

#define B_  2
#define N_  2048
#define E_  1024
#define H_  16
#define HD_ 64
#define M_  (B_*N_)

typedef short bf16x8 __attribute__((ext_vector_type(8)));
typedef float f32x4 __attribute__((ext_vector_type(4)));
typedef unsigned short u16x8 __attribute__((ext_vector_type(8)));

__device__ __forceinline__ unsigned short f2bfu(float f) {
    __hip_bfloat16 h = __float2bfloat16(f);
    return *reinterpret_cast<unsigned short*>(&h);
}
#define MFMA16(a,b,c) __builtin_amdgcn_mfma_f32_16x16x32_bf16((a),(b),(c),0,0,0)

// ---------------------------------------------------------------------------
// Kernel 0: convert Wq,Wk,Wv fp32 -> bf16 into ws region0 (later reused as
// the attention-output buffer; QKV GEMM consumes Wbf before attn runs).
// ---------------------------------------------------------------------------
__global__ __launch_bounds__(256) void wconv_kernel(
    const float* __restrict__ Wq, const float* __restrict__ Wk,
    const float* __restrict__ Wv, unsigned short* __restrict__ wbf)
{
    const int z = blockIdx.y;
    const float* __restrict__ W = (z == 0) ? Wq : (z == 1 ? Wk : Wv);
    const int i0 = (blockIdx.x * 256 + threadIdx.x) * 8;
    const float4 a = *reinterpret_cast<const float4*>(W + i0);
    const float4 b = *reinterpret_cast<const float4*>(W + i0 + 4);
    u16x8 v;
    v[0]=f2bfu(a.x); v[1]=f2bfu(a.y); v[2]=f2bfu(a.z); v[3]=f2bfu(a.w);
    v[4]=f2bfu(b.x); v[5]=f2bfu(b.y); v[6]=f2bfu(b.z); v[7]=f2bfu(b.w);
    *reinterpret_cast<u16x8*>(wbf + (size_t)z * E_ * E_ + i0) = v;
}

// ---------------------------------------------------------------------------
// Kernel 1: QKV projection via MFMA. y = x @ W^T. A-side fp32 x converted at
// staging; B-side bf16 (prepass). Q pre-scaled by 1/8. z==2 writes V^T
// [bh][64 d][2048 n] so attention needs no transpose.
// ---------------------------------------------------------------------------
__global__ __launch_bounds__(256) void qkv_mfma_kernel(
    const float* __restrict__ x, const unsigned short* __restrict__ wbf,
    unsigned short* __restrict__ qkv)
{
    const int z = blockIdx.z;
    const unsigned short* __restrict__ W = wbf + (size_t)z * E_ * E_;
    unsigned short* __restrict__ out = qkv + (size_t)(z + 1) * M_ * E_;
    const int m0 = blockIdx.y * 128;
    const int n0 = blockIdx.x * 128;
    __shared__ unsigned short As[128][72];
    __shared__ unsigned short Bs[128][72];
    const int t = threadIdx.x;
    const int lane = t & 63;
    const int w = t >> 6, wr = w >> 1, wc = w & 1;
    const int fr = lane & 15, fq = lane >> 4;
    const int srow = t >> 1, scol = (t & 1) * 32;
    f32x4 acc[4][4] = {};

    for (int k0 = 0; k0 < E_; k0 += 64) {
        float4 a4[8];
        u16x8 b8[4];
        const float4* ap = reinterpret_cast<const float4*>(x + (size_t)(m0 + srow) * E_ + k0 + scol);
        const u16x8* bp = reinterpret_cast<const u16x8*>(W + (size_t)(n0 + srow) * E_ + k0 + scol);
        #pragma unroll
        for (int i = 0; i < 8; ++i) a4[i] = ap[i];
        #pragma unroll
        for (int i = 0; i < 4; ++i) b8[i] = bp[i];
        __syncthreads();
        #pragma unroll
        for (int j = 0; j < 4; ++j) {
            u16x8 va;
            va[0]=f2bfu(a4[2*j].x); va[1]=f2bfu(a4[2*j].y); va[2]=f2bfu(a4[2*j].z); va[3]=f2bfu(a4[2*j].w);
            va[4]=f2bfu(a4[2*j+1].x); va[5]=f2bfu(a4[2*j+1].y); va[6]=f2bfu(a4[2*j+1].z); va[7]=f2bfu(a4[2*j+1].w);
            *reinterpret_cast<u16x8*>(&As[srow][scol + 8*j]) = va;
            *reinterpret_cast<u16x8*>(&Bs[srow][scol + 8*j]) = b8[j];
        }
        __syncthreads();
        #pragma unroll
        for (int ks = 0; ks < 2; ++ks) {
            bf16x8 af[4], bfv[4];
            #pragma unroll
            for (int mf = 0; mf < 4; ++mf)
                af[mf] = *reinterpret_cast<const bf16x8*>(&As[wr*64 + mf*16 + fr][ks*32 + fq*8]);
            #pragma unroll
            for (int nf = 0; nf < 4; ++nf)
                bfv[nf] = *reinterpret_cast<const bf16x8*>(&Bs[wc*64 + nf*16 + fr][ks*32 + fq*8]);
            #pragma unroll
            for (int mf = 0; mf < 4; ++mf)
                #pragma unroll
                for (int nf = 0; nf < 4; ++nf)
                    acc[mf][nf] = MFMA16(af[mf], bfv[nf], acc[mf][nf]);
        }
    }

    const float scale = (z == 0) ? 0.125f : 1.0f;
    #pragma unroll
    for (int mf = 0; mf < 4; ++mf) {
        #pragma unroll
        for (int r = 0; r < 4; ++r) {
            const int m = m0 + wr*64 + mf*16 + fq*4 + r;
            const int b = m >> 11, npos = m & (N_ - 1);
            #pragma unroll
            for (int nf = 0; nf < 4; ++nf) {
                const int n = n0 + wc*64 + nf*16 + fr;
                const int h = n >> 6, d = n & 63;
                const unsigned short val = f2bfu(acc[mf][nf][r] * scale);
                if (z == 2)   // V^T: [bh][d][npos]
                    out[(((size_t)(b*H_ + h))*HD_ + d)*N_ + npos] = val;
                else
                    out[(((size_t)(b*H_ + h))*N_ + npos)*HD_ + d] = val;
            }
        }
    }
}

// ---------------------------------------------------------------------------
// Kernel 2: MFMA flash attention. 4 waves, 128 q-rows/block (32/wave).
// Q fragments in registers; K and V^T staged vectorized in LDS; P via LDS
// (wave-private rows). Heavy-first block order for causal balance.
// ---------------------------------------------------------------------------
__global__ __launch_bounds__(256) void attn_mfma_kernel(
    const unsigned short* __restrict__ ws, unsigned short* __restrict__ attn_out)
{
    const int qtile = (gridDim.x - 1) - blockIdx.x;   // heavy blocks first
    const int bh = blockIdx.y;
    const int q0 = qtile * 128;
    const unsigned short* Qp  = ws + (size_t)M_ * E_ + (size_t)bh * N_ * HD_;
    const unsigned short* Kp  = ws + 2*(size_t)M_ * E_ + (size_t)bh * N_ * HD_;
    const unsigned short* Vtp = ws + 3*(size_t)M_ * E_ + (size_t)bh * N_ * HD_;
    __shared__ unsigned short Ks[64][72], Vt[64][72], Ps[128][72];
    const int t = threadIdx.x;
    const int lane = t & 63, w = t >> 6;
    const int fr = lane & 15, fq = lane >> 4;
    const int srow = t >> 2, sc0 = (t & 3) * 16;
    const int wqs = q0 + w * 32;          // wave's first q-row

    bf16x8 qfr[2][2];
    #pragma unroll
    for (int qf = 0; qf < 2; ++qf)
        #pragma unroll
        for (int ks = 0; ks < 2; ++ks)
            qfr[qf][ks] = *reinterpret_cast<const bf16x8*>(
                Qp + (size_t)(wqs + qf*16 + fr) * HD_ + ks*32 + fq*8);

    float m_run[8], l_run[8];
    #pragma unroll
    for (int i = 0; i < 8; ++i) { m_run[i] = -1e30f; l_run[i] = 0.f; }
    f32x4 o[2][4] = {};

    const int KT = 2 * qtile + 2;
    for (int kt = 0; kt < KT; ++kt) {
        const int k0 = kt * 64;
        __syncthreads();
        {
            const u16x8* ksrc = reinterpret_cast<const u16x8*>(Kp + (size_t)(k0 + srow) * HD_ + sc0);
            u16x8 kv0 = ksrc[0], kv1 = ksrc[1];
            const u16x8* vsrc = reinterpret_cast<const u16x8*>(Vtp + (size_t)srow * N_ + k0 + sc0);
            u16x8 vv0 = vsrc[0], vv1 = vsrc[1];
            *reinterpret_cast<u16x8*>(&Ks[srow][sc0])     = kv0;
            *reinterpret_cast<u16x8*>(&Ks[srow][sc0 + 8]) = kv1;
            *reinterpret_cast<u16x8*>(&Vt[srow][sc0])     = vv0;
            *reinterpret_cast<u16x8*>(&Vt[srow][sc0 + 8]) = vv1;
        }
        __syncthreads();

        if (k0 > wqs + 31) continue;      // fully masked for this wave

        // S = Q K^T  (wave: 32 q-rows x 64 k-cols)
        f32x4 s[2][4] = {};
        #pragma unroll
        for (int ks = 0; ks < 2; ++ks) {
            bf16x8 bk[4];
            #pragma unroll
            for (int nf = 0; nf < 4; ++nf)
                bk[nf] = *reinterpret_cast<const bf16x8*>(&Ks[nf*16 + fr][ks*32 + fq*8]);
            #pragma unroll
            for (int qf = 0; qf < 2; ++qf)
                #pragma unroll
                for (int nf = 0; nf < 4; ++nf)
                    s[qf][nf] = MFMA16(qfr[qf][ks], bk[nf], s[qf][nf]);
        }
        if (k0 + 63 > wqs) {              // diagonal region: apply causal mask
            #pragma unroll
            for (int qf = 0; qf < 2; ++qf)
                #pragma unroll
                for (int nf = 0; nf < 4; ++nf)
                    #pragma unroll
                    for (int r = 0; r < 4; ++r) {
                        const int ql = wqs + qf*16 + fq*4 + r;
                        const int kl = k0 + nf*16 + fr;
                        if (kl > ql) s[qf][nf][r] = -1e30f;
                    }
        }

        // online softmax (rows live in 16-lane groups; reduce over fr bits)
        float scale_[8];
        #pragma unroll
        for (int qf = 0; qf < 2; ++qf)
            #pragma unroll
            for (int r = 0; r < 4; ++r) {
                const int ri = qf*4 + r;
                float pm = fmaxf(fmaxf(s[qf][0][r], s[qf][1][r]),
                                 fmaxf(s[qf][2][r], s[qf][3][r]));
                pm = fmaxf(pm, __shfl_xor(pm, 1));
                pm = fmaxf(pm, __shfl_xor(pm, 2));
                pm = fmaxf(pm, __shfl_xor(pm, 4));
                pm = fmaxf(pm, __shfl_xor(pm, 8));
                const float mnew = fmaxf(m_run[ri], pm);
                scale_[ri] = __expf(m_run[ri] - mnew);
                m_run[ri] = mnew;
            }
        float rs[8] = {0.f,0.f,0.f,0.f,0.f,0.f,0.f,0.f};
        #pragma unroll
        for (int qf = 0; qf < 2; ++qf)
            #pragma unroll
            for (int nf = 0; nf < 4; ++nf)
                #pragma unroll
                for (int r = 0; r < 4; ++r) {
                    const int ri = qf*4 + r;
                    const float p = __expf(s[qf][nf][r] - m_run[ri]);
                    rs[ri] += p;
                    Ps[w*32 + qf*16 + fq*4 + r][nf*16 + fr] = f2bfu(p);
                }
        #pragma unroll
        for (int ri = 0; ri < 8; ++ri) {
            float v = rs[ri];
            v += __shfl_xor(v, 1);
            v += __shfl_xor(v, 2);
            v += __shfl_xor(v, 4);
            v += __shfl_xor(v, 8);
            l_run[ri] = l_run[ri] * scale_[ri] + v;
        }
        #pragma unroll
        for (int qf = 0; qf < 2; ++qf)
            #pragma unroll
            for (int df = 0; df < 4; ++df)
                #pragma unroll
                for (int r = 0; r < 4; ++r)
                    o[qf][df][r] *= scale_[qf*4 + r];

        // O += P V  (Ps rows wave-private; same-wave LDS write->read)
        #pragma unroll
        for (int ks = 0; ks < 2; ++ks) {
            bf16x8 bv[4];
            #pragma unroll
            for (int df = 0; df < 4; ++df)
                bv[df] = *reinterpret_cast<const bf16x8*>(&Vt[df*16 + fr][ks*32 + fq*8]);
            #pragma unroll
            for (int qf = 0; qf < 2; ++qf) {
                bf16x8 apv = *reinterpret_cast<const bf16x8*>(&Ps[w*32 + qf*16 + fr][ks*32 + fq*8]);
                #pragma unroll
                for (int df = 0; df < 4; ++df)
                    o[qf][df] = MFMA16(apv, bv[df], o[qf][df]);
            }
        }
    }

    const int b = bh >> 4, h = bh & 15;
    #pragma unroll
    for (int qf = 0; qf < 2; ++qf)
        #pragma unroll
        for (int r = 0; r < 4; ++r) {
            const int q = wqs + qf*16 + fq*4 + r;
            const float inv = 1.0f / l_run[qf*4 + r];
            #pragma unroll
            for (int df = 0; df < 4; ++df)
                attn_out[((size_t)(b*N_ + q))*E_ + h*64 + df*16 + fr] =
                    f2bfu(o[qf][df][r] * inv);
        }
}

// ---------------------------------------------------------------------------
// Kernel 3: out = attn @ Wo^T + bo  (A bf16, Wo fp32->bf16 staged, out fp32)
// ---------------------------------------------------------------------------
__global__ __launch_bounds__(256) void out_mfma_kernel(
    const unsigned short* __restrict__ A, const float* __restrict__ Wo,
    const float* __restrict__ bo, float* __restrict__ out)
{
    const int m0 = blockIdx.y * 128;
    const int n0 = blockIdx.x * 128;
    __shared__ unsigned short As[128][72];
    __shared__ unsigned short Bs[128][72];
    const int t = threadIdx.x;
    const int lane = t & 63;
    const int w = t >> 6, wr = w >> 1, wc = w & 1;
    const int fr = lane & 15, fq = lane >> 4;
    const int srow = t >> 1, scol = (t & 1) * 32;
    f32x4 acc[4][4] = {};

    for (int k0 = 0; k0 < E_; k0 += 64) {
        u16x8 a8[4];
        float4 b4[8];
        const u16x8* ap = reinterpret_cast<const u16x8*>(A + (size_t)(m0 + srow) * E_ + k0 + scol);
        const float4* bp = reinterpret_cast<const float4*>(Wo + (size_t)(n0 + srow) * E_ + k0 + scol);
        #pragma unroll
        for (int i = 0; i < 4; ++i) a8[i] = ap[i];
        #pragma unroll
        for (int i = 0; i < 8; ++i) b4[i] = bp[i];
        __syncthreads();
        #pragma unroll
        for (int j = 0; j < 4; ++j) {
            u16x8 vb;
            vb[0]=f2bfu(b4[2*j].x); vb[1]=f2bfu(b4[2*j].y); vb[2]=f2bfu(b4[2*j].z); vb[3]=f2bfu(b4[2*j].w);
            vb[4]=f2bfu(b4[2*j+1].x); vb[5]=f2bfu(b4[2*j+1].y); vb[6]=f2bfu(b4[2*j+1].z); vb[7]=f2bfu(b4[2*j+1].w);
            *reinterpret_cast<u16x8*>(&As[srow][scol + 8*j]) = a8[j];
            *reinterpret_cast<u16x8*>(&Bs[srow][scol + 8*j]) = vb;
        }
        __syncthreads();
        #pragma unroll
        for (int ks = 0; ks < 2; ++ks) {
            bf16x8 af[4], bfv[4];
            #pragma unroll
            for (int mf = 0; mf < 4; ++mf)
                af[mf] = *reinterpret_cast<const bf16x8*>(&As[wr*64 + mf*16 + fr][ks*32 + fq*8]);
            #pragma unroll
            for (int nf = 0; nf < 4; ++nf)
                bfv[nf] = *reinterpret_cast<const bf16x8*>(&Bs[wc*64 + nf*16 + fr][ks*32 + fq*8]);
            #pragma unroll
            for (int mf = 0; mf < 4; ++mf)
                #pragma unroll
                for (int nf = 0; nf < 4; ++nf)
                    acc[mf][nf] = MFMA16(af[mf], bfv[nf], acc[mf][nf]);
        }
    }

    #pragma unroll
    for (int mf = 0; mf < 4; ++mf) {
        #pragma unroll
        for (int r = 0; r < 4; ++r) {
            const int m = m0 + wr*64 + mf*16 + fq*4 + r;
            #pragma unroll
            for (int nf = 0; nf < 4; ++nf) {
                const int n = n0 + wc*64 + nf*16 + fr;
                out[(size_t)m * E_ + n] = acc[mf][nf][r] + bo[n];
            }
        }
    }
}

extern "C" void kernel_launch(void* const* d_in, const int* in_sizes, int n_in,
                              void* d_out, int out_size, void* d_ws, size_t ws_size,
                              hipStream_t stream) {
    const float* x  = (const float*)d_in[0];
    // d_in[1] = mask (causal tril, applied analytically)
    const float* Wq = (const float*)d_in[2];
    const float* Wk = (const float*)d_in[3];
    const float* Wv = (const float*)d_in[4];
    const float* Wo = (const float*)d_in[5];
    const float* bo = (const float*)d_in[6];
    float* out = (float*)d_out;

    // ws layout (u16 units): region0 = Wbf (then attn out), then Q, K, Vt
    unsigned short* ws = (unsigned short*)d_ws;
    unsigned short* wbf = ws;                              // 3MB used of 8MB
    unsigned short* attn_ws = ws;                          // reused after QKV

    dim3 g0(E_ * E_ / (256 * 8), 3);
    wconv_kernel<<<g0, 256, 0, stream>>>(Wq, Wk, Wv, wbf);

    dim3 g1(E_ / 128, M_ / 128, 3);
    qkv_mfma_kernel<<<g1, 256, 0, stream>>>(x, wbf, ws);

    dim3 g2(N_ / 128, B_ * H_);
    attn_mfma_kernel<<<g2, 256, 0, stream>>>(ws, attn_ws);

    dim3 g3(E_ / 128, M_ / 128);
    out_mfma_kernel<<<g3, 256, 0, stream>>>(attn_ws, Wo, bo, out);
}

// Round 4
// 219.705 us; speedup vs baseline: 6.1670x; 1.1192x over previous
//
#include <hip/hip_runtime.h>
#include <hip/hip_bf16.h>

#define B_  2
#define N_  2048
#define E_  1024
#define H_  16
#define HD_ 64
#define M_  (B_*N_)

typedef short bf16x8 __attribute__((ext_vector_type(8)));
typedef float f32x4 __attribute__((ext_vector_type(4)));
typedef unsigned short u16x8 __attribute__((ext_vector_type(8)));

__device__ __forceinline__ unsigned short f2bfu(float f) {
    __hip_bfloat16 h = __float2bfloat16(f);
    return *reinterpret_cast<unsigned short*>(&h);
}
#define MFMA16(a,b,c) __builtin_amdgcn_mfma_f32_16x16x32_bf16((a),(b),(c),0,0,0)

// ---------------------------------------------------------------------------
// Kernel 0: convert Wq,Wk,Wv fp32 -> bf16 into ws region0 (later reused as
// the attention-output buffer; QKV GEMM consumes Wbf before attn runs).
// ---------------------------------------------------------------------------
__global__ __launch_bounds__(256) void wconv_kernel(
    const float* __restrict__ Wq, const float* __restrict__ Wk,
    const float* __restrict__ Wv, unsigned short* __restrict__ wbf)
{
    const int z = blockIdx.y;
    const float* __restrict__ W = (z == 0) ? Wq : (z == 1 ? Wk : Wv);
    const int i0 = (blockIdx.x * 256 + threadIdx.x) * 8;
    const float4 a = *reinterpret_cast<const float4*>(W + i0);
    const float4 b = *reinterpret_cast<const float4*>(W + i0 + 4);
    u16x8 v;
    v[0]=f2bfu(a.x); v[1]=f2bfu(a.y); v[2]=f2bfu(a.z); v[3]=f2bfu(a.w);
    v[4]=f2bfu(b.x); v[5]=f2bfu(b.y); v[6]=f2bfu(b.z); v[7]=f2bfu(b.w);
    *reinterpret_cast<u16x8*>(wbf + (size_t)z * E_ * E_ + i0) = v;
}

// ---------------------------------------------------------------------------
// Kernel 1: QKV projection via MFMA. y = x @ W^T. A-side fp32 x converted at
// staging; B-side bf16 (prepass). Q pre-scaled by 1/8. z==2 writes V^T
// [bh][64 d][2048 n] so attention needs no transpose.
// ---------------------------------------------------------------------------
__global__ __launch_bounds__(256) void qkv_mfma_kernel(
    const float* __restrict__ x, const unsigned short* __restrict__ wbf,
    unsigned short* __restrict__ qkv)
{
    const int z = blockIdx.z;
    const unsigned short* __restrict__ W = wbf + (size_t)z * E_ * E_;
    unsigned short* __restrict__ out = qkv + (size_t)(z + 1) * M_ * E_;
    const int m0 = blockIdx.y * 128;
    const int n0 = blockIdx.x * 128;
    __shared__ unsigned short As[128][72];
    __shared__ unsigned short Bs[128][72];
    const int t = threadIdx.x;
    const int lane = t & 63;
    const int w = t >> 6, wr = w >> 1, wc = w & 1;
    const int fr = lane & 15, fq = lane >> 4;
    const int srow = t >> 1, scol = (t & 1) * 32;
    f32x4 acc[4][4] = {};

    for (int k0 = 0; k0 < E_; k0 += 64) {
        float4 a4[8];
        u16x8 b8[4];
        const float4* ap = reinterpret_cast<const float4*>(x + (size_t)(m0 + srow) * E_ + k0 + scol);
        const u16x8* bp = reinterpret_cast<const u16x8*>(W + (size_t)(n0 + srow) * E_ + k0 + scol);
        #pragma unroll
        for (int i = 0; i < 8; ++i) a4[i] = ap[i];
        #pragma unroll
        for (int i = 0; i < 4; ++i) b8[i] = bp[i];
        __syncthreads();
        #pragma unroll
        for (int j = 0; j < 4; ++j) {
            u16x8 va;
            va[0]=f2bfu(a4[2*j].x); va[1]=f2bfu(a4[2*j].y); va[2]=f2bfu(a4[2*j].z); va[3]=f2bfu(a4[2*j].w);
            va[4]=f2bfu(a4[2*j+1].x); va[5]=f2bfu(a4[2*j+1].y); va[6]=f2bfu(a4[2*j+1].z); va[7]=f2bfu(a4[2*j+1].w);
            *reinterpret_cast<u16x8*>(&As[srow][scol + 8*j]) = va;
            *reinterpret_cast<u16x8*>(&Bs[srow][scol + 8*j]) = b8[j];
        }
        __syncthreads();
        #pragma unroll
        for (int ks = 0; ks < 2; ++ks) {
            bf16x8 af[4], bfv[4];
            #pragma unroll
            for (int mf = 0; mf < 4; ++mf)
                af[mf] = *reinterpret_cast<const bf16x8*>(&As[wr*64 + mf*16 + fr][ks*32 + fq*8]);
            #pragma unroll
            for (int nf = 0; nf < 4; ++nf)
                bfv[nf] = *reinterpret_cast<const bf16x8*>(&Bs[wc*64 + nf*16 + fr][ks*32 + fq*8]);
            #pragma unroll
            for (int mf = 0; mf < 4; ++mf)
                #pragma unroll
                for (int nf = 0; nf < 4; ++nf)
                    acc[mf][nf] = MFMA16(af[mf], bfv[nf], acc[mf][nf]);
        }
    }

    const float scale = (z == 0) ? 0.125f : 1.0f;
    #pragma unroll
    for (int mf = 0; mf < 4; ++mf) {
        #pragma unroll
        for (int r = 0; r < 4; ++r) {
            const int m = m0 + wr*64 + mf*16 + fq*4 + r;
            const int b = m >> 11, npos = m & (N_ - 1);
            #pragma unroll
            for (int nf = 0; nf < 4; ++nf) {
                const int n = n0 + wc*64 + nf*16 + fr;
                const int h = n >> 6, d = n & 63;
                const unsigned short val = f2bfu(acc[mf][nf][r] * scale);
                if (z == 2)   // V^T: [bh][d][npos]
                    out[(((size_t)(b*H_ + h))*HD_ + d)*N_ + npos] = val;
                else
                    out[(((size_t)(b*H_ + h))*N_ + npos)*HD_ + d] = val;
            }
        }
    }
}

// ---------------------------------------------------------------------------
// Kernel 2: MFMA flash attention, load-balanced pairing.
// Block x in [0,8): waves 0-3 -> q-tile (15-x) [heavy], waves 4-7 -> q-tile x
// [light], same bh => shared K/V staging. Every block = exactly 34 k-tile
// units of compute. K/V double-buffered through registers (async-stage).
// ---------------------------------------------------------------------------
__global__ __launch_bounds__(512) void attn_mfma_kernel(
    const unsigned short* __restrict__ ws, unsigned short* __restrict__ attn_out)
{
    const int xp = blockIdx.x;            // 0..7
    const int bh = blockIdx.y;            // 0..31
    const unsigned short* Qp  = ws + (size_t)M_ * E_ + (size_t)bh * N_ * HD_;
    const unsigned short* Kp  = ws + 2*(size_t)M_ * E_ + (size_t)bh * N_ * HD_;
    const unsigned short* Vtp = ws + 3*(size_t)M_ * E_ + (size_t)bh * N_ * HD_;
    __shared__ unsigned short Ks[64][72], Vt[64][72], Ps[256][72];
    const int t = threadIdx.x;
    const int lane = t & 63, w = t >> 6;
    const int fr = lane & 15, fq = lane >> 4;
    const int srow = t >> 3, sc0 = (t & 7) * 8;
    // wave's 32 q-rows
    const int qbase = (w < 4) ? ((15 - xp) * 128 + w * 32)
                              : (xp * 128 + (w - 4) * 32);
    const int KT = 2 * (15 - xp) + 2;     // heavy tile's k-range (superset)

    bf16x8 qfr[2][2];
    #pragma unroll
    for (int qf = 0; qf < 2; ++qf)
        #pragma unroll
        for (int ks = 0; ks < 2; ++ks)
            qfr[qf][ks] = *reinterpret_cast<const bf16x8*>(
                Qp + (size_t)(qbase + qf*16 + fr) * HD_ + ks*32 + fq*8);

    float m_run[8], l_run[8];
    #pragma unroll
    for (int i = 0; i < 8; ++i) { m_run[i] = -1e30f; l_run[i] = 0.f; }
    f32x4 o[2][4] = {};

    // prefetch tile 0 into registers
    u16x8 kreg = *reinterpret_cast<const u16x8*>(Kp + (size_t)srow * HD_ + sc0);
    u16x8 vreg = *reinterpret_cast<const u16x8*>(Vtp + (size_t)srow * N_ + sc0);

    for (int kt = 0; kt < KT; ++kt) {
        const int k0 = kt * 64;
        __syncthreads();                  // prev tile's LDS reads complete
        *reinterpret_cast<u16x8*>(&Ks[srow][sc0]) = kreg;
        *reinterpret_cast<u16x8*>(&Vt[srow][sc0]) = vreg;
        __syncthreads();                  // staged tile visible
        if (kt + 1 < KT) {                // async prefetch next tile
            kreg = *reinterpret_cast<const u16x8*>(Kp + (size_t)(k0 + 64 + srow) * HD_ + sc0);
            vreg = *reinterpret_cast<const u16x8*>(Vtp + (size_t)srow * N_ + k0 + 64 + sc0);
        }
        if (k0 > qbase + 31) continue;    // fully masked for this wave

        // S = Q K^T  (wave: 32 q-rows x 64 k-cols)
        f32x4 s[2][4] = {};
        #pragma unroll
        for (int ks = 0; ks < 2; ++ks) {
            bf16x8 bk[4];
            #pragma unroll
            for (int nf = 0; nf < 4; ++nf)
                bk[nf] = *reinterpret_cast<const bf16x8*>(&Ks[nf*16 + fr][ks*32 + fq*8]);
            #pragma unroll
            for (int qf = 0; qf < 2; ++qf)
                #pragma unroll
                for (int nf = 0; nf < 4; ++nf)
                    s[qf][nf] = MFMA16(qfr[qf][ks], bk[nf], s[qf][nf]);
        }
        if (k0 + 63 > qbase) {            // diagonal region: causal mask
            #pragma unroll
            for (int qf = 0; qf < 2; ++qf)
                #pragma unroll
                for (int nf = 0; nf < 4; ++nf)
                    #pragma unroll
                    for (int r = 0; r < 4; ++r) {
                        const int ql = qbase + qf*16 + fq*4 + r;
                        const int kl = k0 + nf*16 + fr;
                        if (kl > ql) s[qf][nf][r] = -1e30f;
                    }
        }

        // online softmax (rows live in 16-lane groups; reduce over fr bits)
        float scale_[8];
        #pragma unroll
        for (int qf = 0; qf < 2; ++qf)
            #pragma unroll
            for (int r = 0; r < 4; ++r) {
                const int ri = qf*4 + r;
                float pm = fmaxf(fmaxf(s[qf][0][r], s[qf][1][r]),
                                 fmaxf(s[qf][2][r], s[qf][3][r]));
                pm = fmaxf(pm, __shfl_xor(pm, 1));
                pm = fmaxf(pm, __shfl_xor(pm, 2));
                pm = fmaxf(pm, __shfl_xor(pm, 4));
                pm = fmaxf(pm, __shfl_xor(pm, 8));
                const float mnew = fmaxf(m_run[ri], pm);
                scale_[ri] = __expf(m_run[ri] - mnew);
                m_run[ri] = mnew;
            }
        float rs[8] = {0.f,0.f,0.f,0.f,0.f,0.f,0.f,0.f};
        #pragma unroll
        for (int qf = 0; qf < 2; ++qf)
            #pragma unroll
            for (int nf = 0; nf < 4; ++nf)
                #pragma unroll
                for (int r = 0; r < 4; ++r) {
                    const int ri = qf*4 + r;
                    const float p = __expf(s[qf][nf][r] - m_run[ri]);
                    rs[ri] += p;
                    Ps[w*32 + qf*16 + fq*4 + r][nf*16 + fr] = f2bfu(p);
                }
        #pragma unroll
        for (int ri = 0; ri < 8; ++ri) {
            float v = rs[ri];
            v += __shfl_xor(v, 1);
            v += __shfl_xor(v, 2);
            v += __shfl_xor(v, 4);
            v += __shfl_xor(v, 8);
            l_run[ri] = l_run[ri] * scale_[ri] + v;
        }
        #pragma unroll
        for (int qf = 0; qf < 2; ++qf)
            #pragma unroll
            for (int df = 0; df < 4; ++df)
                #pragma unroll
                for (int r = 0; r < 4; ++r)
                    o[qf][df][r] *= scale_[qf*4 + r];

        // O += P V  (Ps rows wave-private; same-wave LDS write->read)
        #pragma unroll
        for (int ks = 0; ks < 2; ++ks) {
            bf16x8 bv[4];
            #pragma unroll
            for (int df = 0; df < 4; ++df)
                bv[df] = *reinterpret_cast<const bf16x8*>(&Vt[df*16 + fr][ks*32 + fq*8]);
            #pragma unroll
            for (int qf = 0; qf < 2; ++qf) {
                bf16x8 apv = *reinterpret_cast<const bf16x8*>(&Ps[w*32 + qf*16 + fr][ks*32 + fq*8]);
                #pragma unroll
                for (int df = 0; df < 4; ++df)
                    o[qf][df] = MFMA16(apv, bv[df], o[qf][df]);
            }
        }
    }

    const int b = bh >> 4, h = bh & 15;
    #pragma unroll
    for (int qf = 0; qf < 2; ++qf)
        #pragma unroll
        for (int r = 0; r < 4; ++r) {
            const int q = qbase + qf*16 + fq*4 + r;
            const float inv = 1.0f / l_run[qf*4 + r];
            #pragma unroll
            for (int df = 0; df < 4; ++df)
                attn_out[((size_t)(b*N_ + q))*E_ + h*64 + df*16 + fr] =
                    f2bfu(o[qf][df][r] * inv);
        }
}

// ---------------------------------------------------------------------------
// Kernel 3: out = attn @ Wo^T + bo  (A bf16, Wo fp32->bf16 staged, out fp32)
// ---------------------------------------------------------------------------
__global__ __launch_bounds__(256) void out_mfma_kernel(
    const unsigned short* __restrict__ A, const float* __restrict__ Wo,
    const float* __restrict__ bo, float* __restrict__ out)
{
    const int m0 = blockIdx.y * 128;
    const int n0 = blockIdx.x * 128;
    __shared__ unsigned short As[128][72];
    __shared__ unsigned short Bs[128][72];
    const int t = threadIdx.x;
    const int lane = t & 63;
    const int w = t >> 6, wr = w >> 1, wc = w & 1;
    const int fr = lane & 15, fq = lane >> 4;
    const int srow = t >> 1, scol = (t & 1) * 32;
    f32x4 acc[4][4] = {};

    for (int k0 = 0; k0 < E_; k0 += 64) {
        u16x8 a8[4];
        float4 b4[8];
        const u16x8* ap = reinterpret_cast<const u16x8*>(A + (size_t)(m0 + srow) * E_ + k0 + scol);
        const float4* bp = reinterpret_cast<const float4*>(Wo + (size_t)(n0 + srow) * E_ + k0 + scol);
        #pragma unroll
        for (int i = 0; i < 4; ++i) a8[i] = ap[i];
        #pragma unroll
        for (int i = 0; i < 8; ++i) b4[i] = bp[i];
        __syncthreads();
        #pragma unroll
        for (int j = 0; j < 4; ++j) {
            u16x8 vb;
            vb[0]=f2bfu(b4[2*j].x); vb[1]=f2bfu(b4[2*j].y); vb[2]=f2bfu(b4[2*j].z); vb[3]=f2bfu(b4[2*j].w);
            vb[4]=f2bfu(b4[2*j+1].x); vb[5]=f2bfu(b4[2*j+1].y); vb[6]=f2bfu(b4[2*j+1].z); vb[7]=f2bfu(b4[2*j+1].w);
            *reinterpret_cast<u16x8*>(&As[srow][scol + 8*j]) = a8[j];
            *reinterpret_cast<u16x8*>(&Bs[srow][scol + 8*j]) = vb;
        }
        __syncthreads();
        #pragma unroll
        for (int ks = 0; ks < 2; ++ks) {
            bf16x8 af[4], bfv[4];
            #pragma unroll
            for (int mf = 0; mf < 4; ++mf)
                af[mf] = *reinterpret_cast<const bf16x8*>(&As[wr*64 + mf*16 + fr][ks*32 + fq*8]);
            #pragma unroll
            for (int nf = 0; nf < 4; ++nf)
                bfv[nf] = *reinterpret_cast<const bf16x8*>(&Bs[wc*64 + nf*16 + fr][ks*32 + fq*8]);
            #pragma unroll
            for (int mf = 0; mf < 4; ++mf)
                #pragma unroll
                for (int nf = 0; nf < 4; ++nf)
                    acc[mf][nf] = MFMA16(af[mf], bfv[nf], acc[mf][nf]);
        }
    }

    #pragma unroll
    for (int mf = 0; mf < 4; ++mf) {
        #pragma unroll
        for (int r = 0; r < 4; ++r) {
            const int m = m0 + wr*64 + mf*16 + fq*4 + r;
            #pragma unroll
            for (int nf = 0; nf < 4; ++nf) {
                const int n = n0 + wc*64 + nf*16 + fr;
                out[(size_t)m * E_ + n] = acc[mf][nf][r] + bo[n];
            }
        }
    }
}

extern "C" void kernel_launch(void* const* d_in, const int* in_sizes, int n_in,
                              void* d_out, int out_size, void* d_ws, size_t ws_size,
                              hipStream_t stream) {
    const float* x  = (const float*)d_in[0];
    // d_in[1] = mask (causal tril, applied analytically)
    const float* Wq = (const float*)d_in[2];
    const float* Wk = (const float*)d_in[3];
    const float* Wv = (const float*)d_in[4];
    const float* Wo = (const float*)d_in[5];
    const float* bo = (const float*)d_in[6];
    float* out = (float*)d_out;

    // ws layout (u16 units): region0 = Wbf (then attn out), then Q, K, Vt
    unsigned short* ws = (unsigned short*)d_ws;
    unsigned short* wbf = ws;
    unsigned short* attn_ws = ws;                          // reused after QKV

    dim3 g0(E_ * E_ / (256 * 8), 3);
    wconv_kernel<<<g0, 256, 0, stream>>>(Wq, Wk, Wv, wbf);

    dim3 g1(E_ / 128, M_ / 128, 3);
    qkv_mfma_kernel<<<g1, 256, 0, stream>>>(x, wbf, ws);

    dim3 g2(8, B_ * H_);
    attn_mfma_kernel<<<g2, 512, 0, stream>>>(ws, attn_ws);

    dim3 g3(E_ / 128, M_ / 128);
    out_mfma_kernel<<<g3, 256, 0, stream>>>(attn_ws, Wo, bo, out);
}

// Round 5
// 201.045 us; speedup vs baseline: 6.7394x; 1.0928x over previous
//
#include <hip/hip_runtime.h>
#include <hip/hip_bf16.h>

#define B_  2
#define N_  2048
#define E_  1024
#define H_  16
#define HD_ 64
#define M_  (B_*N_)

typedef short bf16x8 __attribute__((ext_vector_type(8)));
typedef float f32x4 __attribute__((ext_vector_type(4)));
typedef unsigned short u16x8 __attribute__((ext_vector_type(8)));

__device__ __forceinline__ unsigned short f2bfu(float f) {
    __hip_bfloat16 h = __float2bfloat16(f);
    return *reinterpret_cast<unsigned short*>(&h);
}
#define MFMA16(a,b,c) __builtin_amdgcn_mfma_f32_16x16x32_bf16((a),(b),(c),0,0,0)

// ---------------------------------------------------------------------------
// Kernel 0: generic fp32 -> bf16 conversion (used for Wq,Wk,Wv pre-attn and
// Wo post-attn). One element range per launch: 2048 elems/block.
// ---------------------------------------------------------------------------
__global__ __launch_bounds__(256) void fconv_kernel(
    const float* __restrict__ src, unsigned short* __restrict__ dst)
{
    const int i0 = (blockIdx.x * 256 + threadIdx.x) * 8;
    const float4 a = *reinterpret_cast<const float4*>(src + i0);
    const float4 b = *reinterpret_cast<const float4*>(src + i0 + 4);
    u16x8 v;
    v[0]=f2bfu(a.x); v[1]=f2bfu(a.y); v[2]=f2bfu(a.z); v[3]=f2bfu(a.w);
    v[4]=f2bfu(b.x); v[5]=f2bfu(b.y); v[6]=f2bfu(b.z); v[7]=f2bfu(b.w);
    *reinterpret_cast<u16x8*>(dst + i0) = v;
}

// ---------------------------------------------------------------------------
// Kernel 1: QKV projection via MFMA, 2-phase prefetch pipeline.
// y = x @ W^T. A-side fp32 x converted at LDS-write; B-side bf16 (prepass).
// Loads for tile t+1 issued before compute(t) -> latency hidden under MFMA.
// Q pre-scaled by 1/8. z==2 writes V^T [bh][64 d][2048 n].
// ---------------------------------------------------------------------------
__global__ __launch_bounds__(256) void qkv_mfma_kernel(
    const float* __restrict__ x, const unsigned short* __restrict__ wbf,
    unsigned short* __restrict__ qkv)
{
    const int z = blockIdx.z;
    const unsigned short* __restrict__ W = wbf + (size_t)z * E_ * E_;
    unsigned short* __restrict__ out = qkv + (size_t)(z + 1) * M_ * E_;
    const int m0 = blockIdx.y * 128;
    const int n0 = blockIdx.x * 128;
    __shared__ unsigned short As[128][72];
    __shared__ unsigned short Bs[128][72];
    const int t = threadIdx.x;
    const int lane = t & 63;
    const int w = t >> 6, wr = w >> 1, wc = w & 1;
    const int fr = lane & 15, fq = lane >> 4;
    const int srow = t >> 1, scol = (t & 1) * 32;
    f32x4 acc[4][4] = {};

    const float* arow = x + (size_t)(m0 + srow) * E_ + scol;
    const unsigned short* brow = W + (size_t)(n0 + srow) * E_ + scol;

    float4 a4[8];
    u16x8 b8[4];
    #pragma unroll
    for (int i = 0; i < 8; ++i) a4[i] = reinterpret_cast<const float4*>(arow)[i];
    #pragma unroll
    for (int i = 0; i < 4; ++i) b8[i] = reinterpret_cast<const u16x8*>(brow)[i];

    for (int k0 = 0; k0 < E_; k0 += 64) {
        __syncthreads();                      // prev tile's ds_reads complete
        #pragma unroll
        for (int j = 0; j < 4; ++j) {
            u16x8 va;
            va[0]=f2bfu(a4[2*j].x); va[1]=f2bfu(a4[2*j].y); va[2]=f2bfu(a4[2*j].z); va[3]=f2bfu(a4[2*j].w);
            va[4]=f2bfu(a4[2*j+1].x); va[5]=f2bfu(a4[2*j+1].y); va[6]=f2bfu(a4[2*j+1].z); va[7]=f2bfu(a4[2*j+1].w);
            *reinterpret_cast<u16x8*>(&As[srow][scol + 8*j]) = va;
            *reinterpret_cast<u16x8*>(&Bs[srow][scol + 8*j]) = b8[j];
        }
        __syncthreads();                      // staged tile visible
        if (k0 + 64 < E_) {                   // prefetch next tile (hides under MFMA)
            #pragma unroll
            for (int i = 0; i < 8; ++i)
                a4[i] = reinterpret_cast<const float4*>(arow + k0 + 64)[i];
            #pragma unroll
            for (int i = 0; i < 4; ++i)
                b8[i] = reinterpret_cast<const u16x8*>(brow + k0 + 64)[i];
        }
        #pragma unroll
        for (int ks = 0; ks < 2; ++ks) {
            bf16x8 af[4], bfv[4];
            #pragma unroll
            for (int mf = 0; mf < 4; ++mf)
                af[mf] = *reinterpret_cast<const bf16x8*>(&As[wr*64 + mf*16 + fr][ks*32 + fq*8]);
            #pragma unroll
            for (int nf = 0; nf < 4; ++nf)
                bfv[nf] = *reinterpret_cast<const bf16x8*>(&Bs[wc*64 + nf*16 + fr][ks*32 + fq*8]);
            #pragma unroll
            for (int mf = 0; mf < 4; ++mf)
                #pragma unroll
                for (int nf = 0; nf < 4; ++nf)
                    acc[mf][nf] = MFMA16(af[mf], bfv[nf], acc[mf][nf]);
        }
    }

    const float scale = (z == 0) ? 0.125f : 1.0f;
    #pragma unroll
    for (int mf = 0; mf < 4; ++mf) {
        #pragma unroll
        for (int r = 0; r < 4; ++r) {
            const int m = m0 + wr*64 + mf*16 + fq*4 + r;
            const int b = m >> 11, npos = m & (N_ - 1);
            #pragma unroll
            for (int nf = 0; nf < 4; ++nf) {
                const int n = n0 + wc*64 + nf*16 + fr;
                const int h = n >> 6, d = n & 63;
                const unsigned short val = f2bfu(acc[mf][nf][r] * scale);
                if (z == 2)   // V^T: [bh][d][npos]
                    out[(((size_t)(b*H_ + h))*HD_ + d)*N_ + npos] = val;
                else
                    out[(((size_t)(b*H_ + h))*N_ + npos)*HD_ + d] = val;
            }
        }
    }
}

// ---------------------------------------------------------------------------
// Kernel 2: MFMA flash attention, load-balanced pairing (unchanged from R3).
// ---------------------------------------------------------------------------
__global__ __launch_bounds__(512) void attn_mfma_kernel(
    const unsigned short* __restrict__ ws, unsigned short* __restrict__ attn_out)
{
    const int xp = blockIdx.x;            // 0..7
    const int bh = blockIdx.y;            // 0..31
    const unsigned short* Qp  = ws + (size_t)M_ * E_ + (size_t)bh * N_ * HD_;
    const unsigned short* Kp  = ws + 2*(size_t)M_ * E_ + (size_t)bh * N_ * HD_;
    const unsigned short* Vtp = ws + 3*(size_t)M_ * E_ + (size_t)bh * N_ * HD_;
    __shared__ unsigned short Ks[64][72], Vt[64][72], Ps[256][72];
    const int t = threadIdx.x;
    const int lane = t & 63, w = t >> 6;
    const int fr = lane & 15, fq = lane >> 4;
    const int srow = t >> 3, sc0 = (t & 7) * 8;
    const int qbase = (w < 4) ? ((15 - xp) * 128 + w * 32)
                              : (xp * 128 + (w - 4) * 32);
    const int KT = 2 * (15 - xp) + 2;     // heavy tile's k-range (superset)

    bf16x8 qfr[2][2];
    #pragma unroll
    for (int qf = 0; qf < 2; ++qf)
        #pragma unroll
        for (int ks = 0; ks < 2; ++ks)
            qfr[qf][ks] = *reinterpret_cast<const bf16x8*>(
                Qp + (size_t)(qbase + qf*16 + fr) * HD_ + ks*32 + fq*8);

    float m_run[8], l_run[8];
    #pragma unroll
    for (int i = 0; i < 8; ++i) { m_run[i] = -1e30f; l_run[i] = 0.f; }
    f32x4 o[2][4] = {};

    u16x8 kreg = *reinterpret_cast<const u16x8*>(Kp + (size_t)srow * HD_ + sc0);
    u16x8 vreg = *reinterpret_cast<const u16x8*>(Vtp + (size_t)srow * N_ + sc0);

    for (int kt = 0; kt < KT; ++kt) {
        const int k0 = kt * 64;
        __syncthreads();
        *reinterpret_cast<u16x8*>(&Ks[srow][sc0]) = kreg;
        *reinterpret_cast<u16x8*>(&Vt[srow][sc0]) = vreg;
        __syncthreads();
        if (kt + 1 < KT) {
            kreg = *reinterpret_cast<const u16x8*>(Kp + (size_t)(k0 + 64 + srow) * HD_ + sc0);
            vreg = *reinterpret_cast<const u16x8*>(Vtp + (size_t)srow * N_ + k0 + 64 + sc0);
        }
        if (k0 > qbase + 31) continue;

        f32x4 s[2][4] = {};
        #pragma unroll
        for (int ks = 0; ks < 2; ++ks) {
            bf16x8 bk[4];
            #pragma unroll
            for (int nf = 0; nf < 4; ++nf)
                bk[nf] = *reinterpret_cast<const bf16x8*>(&Ks[nf*16 + fr][ks*32 + fq*8]);
            #pragma unroll
            for (int qf = 0; qf < 2; ++qf)
                #pragma unroll
                for (int nf = 0; nf < 4; ++nf)
                    s[qf][nf] = MFMA16(qfr[qf][ks], bk[nf], s[qf][nf]);
        }
        if (k0 + 63 > qbase) {
            #pragma unroll
            for (int qf = 0; qf < 2; ++qf)
                #pragma unroll
                for (int nf = 0; nf < 4; ++nf)
                    #pragma unroll
                    for (int r = 0; r < 4; ++r) {
                        const int ql = qbase + qf*16 + fq*4 + r;
                        const int kl = k0 + nf*16 + fr;
                        if (kl > ql) s[qf][nf][r] = -1e30f;
                    }
        }

        float scale_[8];
        #pragma unroll
        for (int qf = 0; qf < 2; ++qf)
            #pragma unroll
            for (int r = 0; r < 4; ++r) {
                const int ri = qf*4 + r;
                float pm = fmaxf(fmaxf(s[qf][0][r], s[qf][1][r]),
                                 fmaxf(s[qf][2][r], s[qf][3][r]));
                pm = fmaxf(pm, __shfl_xor(pm, 1));
                pm = fmaxf(pm, __shfl_xor(pm, 2));
                pm = fmaxf(pm, __shfl_xor(pm, 4));
                pm = fmaxf(pm, __shfl_xor(pm, 8));
                const float mnew = fmaxf(m_run[ri], pm);
                scale_[ri] = __expf(m_run[ri] - mnew);
                m_run[ri] = mnew;
            }
        float rs[8] = {0.f,0.f,0.f,0.f,0.f,0.f,0.f,0.f};
        #pragma unroll
        for (int qf = 0; qf < 2; ++qf)
            #pragma unroll
            for (int nf = 0; nf < 4; ++nf)
                #pragma unroll
                for (int r = 0; r < 4; ++r) {
                    const int ri = qf*4 + r;
                    const float p = __expf(s[qf][nf][r] - m_run[ri]);
                    rs[ri] += p;
                    Ps[w*32 + qf*16 + fq*4 + r][nf*16 + fr] = f2bfu(p);
                }
        #pragma unroll
        for (int ri = 0; ri < 8; ++ri) {
            float v = rs[ri];
            v += __shfl_xor(v, 1);
            v += __shfl_xor(v, 2);
            v += __shfl_xor(v, 4);
            v += __shfl_xor(v, 8);
            l_run[ri] = l_run[ri] * scale_[ri] + v;
        }
        #pragma unroll
        for (int qf = 0; qf < 2; ++qf)
            #pragma unroll
            for (int df = 0; df < 4; ++df)
                #pragma unroll
                for (int r = 0; r < 4; ++r)
                    o[qf][df][r] *= scale_[qf*4 + r];

        #pragma unroll
        for (int ks = 0; ks < 2; ++ks) {
            bf16x8 bv[4];
            #pragma unroll
            for (int df = 0; df < 4; ++df)
                bv[df] = *reinterpret_cast<const bf16x8*>(&Vt[df*16 + fr][ks*32 + fq*8]);
            #pragma unroll
            for (int qf = 0; qf < 2; ++qf) {
                bf16x8 apv = *reinterpret_cast<const bf16x8*>(&Ps[w*32 + qf*16 + fr][ks*32 + fq*8]);
                #pragma unroll
                for (int df = 0; df < 4; ++df)
                    o[qf][df] = MFMA16(apv, bv[df], o[qf][df]);
            }
        }
    }

    const int b = bh >> 4, h = bh & 15;
    #pragma unroll
    for (int qf = 0; qf < 2; ++qf)
        #pragma unroll
        for (int r = 0; r < 4; ++r) {
            const int q = qbase + qf*16 + fq*4 + r;
            const float inv = 1.0f / l_run[qf*4 + r];
            #pragma unroll
            for (int df = 0; df < 4; ++df)
                attn_out[((size_t)(b*N_ + q))*E_ + h*64 + df*16 + fr] =
                    f2bfu(o[qf][df][r] * inv);
        }
}

// ---------------------------------------------------------------------------
// Kernel 3: out = attn @ Wo^T + bo (A bf16, B bf16 prepass), 2-phase prefetch.
// ---------------------------------------------------------------------------
__global__ __launch_bounds__(256) void out_mfma_kernel(
    const unsigned short* __restrict__ A, const unsigned short* __restrict__ Wobf,
    const float* __restrict__ bo, float* __restrict__ out)
{
    const int m0 = blockIdx.y * 128;
    const int n0 = blockIdx.x * 128;
    __shared__ unsigned short As[128][72];
    __shared__ unsigned short Bs[128][72];
    const int t = threadIdx.x;
    const int lane = t & 63;
    const int w = t >> 6, wr = w >> 1, wc = w & 1;
    const int fr = lane & 15, fq = lane >> 4;
    const int srow = t >> 1, scol = (t & 1) * 32;
    f32x4 acc[4][4] = {};

    const unsigned short* arow = A + (size_t)(m0 + srow) * E_ + scol;
    const unsigned short* brow = Wobf + (size_t)(n0 + srow) * E_ + scol;

    u16x8 a8[4], b8[4];
    #pragma unroll
    for (int i = 0; i < 4; ++i) a8[i] = reinterpret_cast<const u16x8*>(arow)[i];
    #pragma unroll
    for (int i = 0; i < 4; ++i) b8[i] = reinterpret_cast<const u16x8*>(brow)[i];

    for (int k0 = 0; k0 < E_; k0 += 64) {
        __syncthreads();
        #pragma unroll
        for (int j = 0; j < 4; ++j) {
            *reinterpret_cast<u16x8*>(&As[srow][scol + 8*j]) = a8[j];
            *reinterpret_cast<u16x8*>(&Bs[srow][scol + 8*j]) = b8[j];
        }
        __syncthreads();
        if (k0 + 64 < E_) {
            #pragma unroll
            for (int i = 0; i < 4; ++i)
                a8[i] = reinterpret_cast<const u16x8*>(arow + k0 + 64)[i];
            #pragma unroll
            for (int i = 0; i < 4; ++i)
                b8[i] = reinterpret_cast<const u16x8*>(brow + k0 + 64)[i];
        }
        #pragma unroll
        for (int ks = 0; ks < 2; ++ks) {
            bf16x8 af[4], bfv[4];
            #pragma unroll
            for (int mf = 0; mf < 4; ++mf)
                af[mf] = *reinterpret_cast<const bf16x8*>(&As[wr*64 + mf*16 + fr][ks*32 + fq*8]);
            #pragma unroll
            for (int nf = 0; nf < 4; ++nf)
                bfv[nf] = *reinterpret_cast<const bf16x8*>(&Bs[wc*64 + nf*16 + fr][ks*32 + fq*8]);
            #pragma unroll
            for (int mf = 0; mf < 4; ++mf)
                #pragma unroll
                for (int nf = 0; nf < 4; ++nf)
                    acc[mf][nf] = MFMA16(af[mf], bfv[nf], acc[mf][nf]);
        }
    }

    #pragma unroll
    for (int mf = 0; mf < 4; ++mf) {
        #pragma unroll
        for (int r = 0; r < 4; ++r) {
            const int m = m0 + wr*64 + mf*16 + fq*4 + r;
            #pragma unroll
            for (int nf = 0; nf < 4; ++nf) {
                const int n = n0 + wc*64 + nf*16 + fr;
                out[(size_t)m * E_ + n] = acc[mf][nf][r] + bo[n];
            }
        }
    }
}

extern "C" void kernel_launch(void* const* d_in, const int* in_sizes, int n_in,
                              void* d_out, int out_size, void* d_ws, size_t ws_size,
                              hipStream_t stream) {
    const float* x  = (const float*)d_in[0];
    // d_in[1] = mask (causal tril, applied analytically)
    const float* Wq = (const float*)d_in[2];
    const float* Wk = (const float*)d_in[3];
    const float* Wv = (const float*)d_in[4];
    const float* Wo = (const float*)d_in[5];
    const float* bo = (const float*)d_in[6];
    float* out = (float*)d_out;

    // ws layout (u16 units), 4 regions of M_*E_:
    //   region0: Wbf(q,k,v) [6MB] -> later attn_out [8MB]
    //   region1: Q          -> later Wo-bf16 (Q dead after attn)
    //   region2: K
    //   region3: V^T
    unsigned short* ws = (unsigned short*)d_ws;
    unsigned short* wbf = ws;
    unsigned short* attn_ws = ws;
    unsigned short* wobf = ws + (size_t)M_ * E_;

    const int cgrid = E_ * E_ / (256 * 8);
    fconv_kernel<<<cgrid, 256, 0, stream>>>(Wq, wbf);
    fconv_kernel<<<cgrid, 256, 0, stream>>>(Wk, wbf + (size_t)E_ * E_);
    fconv_kernel<<<cgrid, 256, 0, stream>>>(Wv, wbf + 2 * (size_t)E_ * E_);

    dim3 g1(E_ / 128, M_ / 128, 3);
    qkv_mfma_kernel<<<g1, 256, 0, stream>>>(x, wbf, ws);

    dim3 g2(8, B_ * H_);
    attn_mfma_kernel<<<g2, 512, 0, stream>>>(ws, attn_ws);

    fconv_kernel<<<cgrid, 256, 0, stream>>>(Wo, wobf);

    dim3 g3(E_ / 128, M_ / 128);
    out_mfma_kernel<<<g3, 256, 0, stream>>>(attn_ws, wobf, bo, out);
}

// Round 6
// 181.501 us; speedup vs baseline: 7.4651x; 1.1077x over previous
//
#include <hip/hip_runtime.h>
#include <hip/hip_bf16.h>

#define B_  2
#define N_  2048
#define E_  1024
#define H_  16
#define HD_ 64
#define M_  (B_*N_)

typedef short bf16x8 __attribute__((ext_vector_type(8)));
typedef float f32x4 __attribute__((ext_vector_type(4)));
typedef unsigned short u16x8 __attribute__((ext_vector_type(8)));

__device__ __forceinline__ unsigned short f2bfu(float f) {
    __hip_bfloat16 h = __float2bfloat16(f);
    return *reinterpret_cast<unsigned short*>(&h);
}
#define MFMA16(a,b,c) __builtin_amdgcn_mfma_f32_16x16x32_bf16((a),(b),(c),0,0,0)

// ---------------------------------------------------------------------------
// Kernel 0: generic fp32 -> bf16 conversion (Wq,Wk,Wv pre-attn; Wo post-attn)
// ---------------------------------------------------------------------------
__global__ __launch_bounds__(256) void fconv_kernel(
    const float* __restrict__ src, unsigned short* __restrict__ dst)
{
    const int i0 = (blockIdx.x * 256 + threadIdx.x) * 8;
    const float4 a = *reinterpret_cast<const float4*>(src + i0);
    const float4 b = *reinterpret_cast<const float4*>(src + i0 + 4);
    u16x8 v;
    v[0]=f2bfu(a.x); v[1]=f2bfu(a.y); v[2]=f2bfu(a.z); v[3]=f2bfu(a.w);
    v[4]=f2bfu(b.x); v[5]=f2bfu(b.y); v[6]=f2bfu(b.z); v[7]=f2bfu(b.w);
    *reinterpret_cast<u16x8*>(dst + i0) = v;
}

// ---------------------------------------------------------------------------
// Kernel 1: QKV projection via MFMA, 2-phase prefetch pipeline (unchanged R4).
// ---------------------------------------------------------------------------
__global__ __launch_bounds__(256) void qkv_mfma_kernel(
    const float* __restrict__ x, const unsigned short* __restrict__ wbf,
    unsigned short* __restrict__ qkv)
{
    const int z = blockIdx.z;
    const unsigned short* __restrict__ W = wbf + (size_t)z * E_ * E_;
    unsigned short* __restrict__ out = qkv + (size_t)(z + 1) * M_ * E_;
    const int m0 = blockIdx.y * 128;
    const int n0 = blockIdx.x * 128;
    __shared__ unsigned short As[128][72];
    __shared__ unsigned short Bs[128][72];
    const int t = threadIdx.x;
    const int lane = t & 63;
    const int w = t >> 6, wr = w >> 1, wc = w & 1;
    const int fr = lane & 15, fq = lane >> 4;
    const int srow = t >> 1, scol = (t & 1) * 32;
    f32x4 acc[4][4] = {};

    const float* arow = x + (size_t)(m0 + srow) * E_ + scol;
    const unsigned short* brow = W + (size_t)(n0 + srow) * E_ + scol;

    float4 a4[8];
    u16x8 b8[4];
    #pragma unroll
    for (int i = 0; i < 8; ++i) a4[i] = reinterpret_cast<const float4*>(arow)[i];
    #pragma unroll
    for (int i = 0; i < 4; ++i) b8[i] = reinterpret_cast<const u16x8*>(brow)[i];

    for (int k0 = 0; k0 < E_; k0 += 64) {
        __syncthreads();
        #pragma unroll
        for (int j = 0; j < 4; ++j) {
            u16x8 va;
            va[0]=f2bfu(a4[2*j].x); va[1]=f2bfu(a4[2*j].y); va[2]=f2bfu(a4[2*j].z); va[3]=f2bfu(a4[2*j].w);
            va[4]=f2bfu(a4[2*j+1].x); va[5]=f2bfu(a4[2*j+1].y); va[6]=f2bfu(a4[2*j+1].z); va[7]=f2bfu(a4[2*j+1].w);
            *reinterpret_cast<u16x8*>(&As[srow][scol + 8*j]) = va;
            *reinterpret_cast<u16x8*>(&Bs[srow][scol + 8*j]) = b8[j];
        }
        __syncthreads();
        if (k0 + 64 < E_) {
            #pragma unroll
            for (int i = 0; i < 8; ++i)
                a4[i] = reinterpret_cast<const float4*>(arow + k0 + 64)[i];
            #pragma unroll
            for (int i = 0; i < 4; ++i)
                b8[i] = reinterpret_cast<const u16x8*>(brow + k0 + 64)[i];
        }
        #pragma unroll
        for (int ks = 0; ks < 2; ++ks) {
            bf16x8 af[4], bfv[4];
            #pragma unroll
            for (int mf = 0; mf < 4; ++mf)
                af[mf] = *reinterpret_cast<const bf16x8*>(&As[wr*64 + mf*16 + fr][ks*32 + fq*8]);
            #pragma unroll
            for (int nf = 0; nf < 4; ++nf)
                bfv[nf] = *reinterpret_cast<const bf16x8*>(&Bs[wc*64 + nf*16 + fr][ks*32 + fq*8]);
            #pragma unroll
            for (int mf = 0; mf < 4; ++mf)
                #pragma unroll
                for (int nf = 0; nf < 4; ++nf)
                    acc[mf][nf] = MFMA16(af[mf], bfv[nf], acc[mf][nf]);
        }
    }

    const float scale = (z == 0) ? 0.125f : 1.0f;
    #pragma unroll
    for (int mf = 0; mf < 4; ++mf) {
        #pragma unroll
        for (int r = 0; r < 4; ++r) {
            const int m = m0 + wr*64 + mf*16 + fq*4 + r;
            const int b = m >> 11, npos = m & (N_ - 1);
            #pragma unroll
            for (int nf = 0; nf < 4; ++nf) {
                const int n = n0 + wc*64 + nf*16 + fr;
                const int h = n >> 6, d = n & 63;
                const unsigned short val = f2bfu(acc[mf][nf][r] * scale);
                if (z == 2)   // V^T: [bh][d][npos]
                    out[(((size_t)(b*H_ + h))*HD_ + d)*N_ + npos] = val;
                else
                    out[(((size_t)(b*H_ + h))*N_ + npos)*HD_ + d] = val;
            }
        }
    }
}

// ---------------------------------------------------------------------------
// Kernel 2: MFMA flash attention. 512 thr / 8 waves; 16 q-rows per wave.
// Pair (heavy=31-xp, light=xp) 64-row q-tiles: waves 0-3 heavy, 4-7 light,
// shared K/V staging. 16 waves/CU (2 blocks x 8). Ps stride 76 = conflict-
// free P writes. Register prefetch of next K/V tile.
// ---------------------------------------------------------------------------
__global__ __launch_bounds__(512) void attn_mfma_kernel(
    const unsigned short* __restrict__ ws, unsigned short* __restrict__ attn_out)
{
    const int xp = blockIdx.x;            // 0..15
    const int bh = blockIdx.y;            // 0..31
    const unsigned short* Qp  = ws + (size_t)M_ * E_ + (size_t)bh * N_ * HD_;
    const unsigned short* Kp  = ws + 2*(size_t)M_ * E_ + (size_t)bh * N_ * HD_;
    const unsigned short* Vtp = ws + 3*(size_t)M_ * E_ + (size_t)bh * N_ * HD_;
    __shared__ unsigned short Ks[64][72], Vt[64][72], Ps[128][76];
    const int t = threadIdx.x;
    const int lane = t & 63, w = t >> 6;
    const int fr = lane & 15, fq = lane >> 4;
    const int srow = t >> 3, sc0 = (t & 7) * 8;
    // wave's 16 q-rows
    const int qbase = (w < 4) ? ((31 - xp) * 64 + w * 16)
                              : (xp * 64 + (w - 4) * 16);
    const int KT = 32 - xp;               // heavy tile's k-range (superset)

    bf16x8 qfr[2];
    #pragma unroll
    for (int ks = 0; ks < 2; ++ks)
        qfr[ks] = *reinterpret_cast<const bf16x8*>(
            Qp + (size_t)(qbase + fr) * HD_ + ks*32 + fq*8);

    float m_run[4], l_run[4];
    #pragma unroll
    for (int i = 0; i < 4; ++i) { m_run[i] = -1e30f; l_run[i] = 0.f; }
    f32x4 o[4] = {};

    u16x8 kreg = *reinterpret_cast<const u16x8*>(Kp + (size_t)srow * HD_ + sc0);
    u16x8 vreg = *reinterpret_cast<const u16x8*>(Vtp + (size_t)srow * N_ + sc0);

    for (int kt = 0; kt < KT; ++kt) {
        const int k0 = kt * 64;
        __syncthreads();                  // prev tile's LDS reads complete
        *reinterpret_cast<u16x8*>(&Ks[srow][sc0]) = kreg;
        *reinterpret_cast<u16x8*>(&Vt[srow][sc0]) = vreg;
        __syncthreads();                  // staged tile visible
        if (kt + 1 < KT) {                // prefetch next tile (hides under compute)
            kreg = *reinterpret_cast<const u16x8*>(Kp + (size_t)(k0 + 64 + srow) * HD_ + sc0);
            vreg = *reinterpret_cast<const u16x8*>(Vtp + (size_t)srow * N_ + k0 + 64 + sc0);
        }
        if (k0 > qbase + 15) continue;    // fully masked for this wave

        // S = Q K^T  (wave: 16 q-rows x 64 k-cols)
        f32x4 s[4] = {};
        #pragma unroll
        for (int ks = 0; ks < 2; ++ks) {
            bf16x8 bk[4];
            #pragma unroll
            for (int nf = 0; nf < 4; ++nf)
                bk[nf] = *reinterpret_cast<const bf16x8*>(&Ks[nf*16 + fr][ks*32 + fq*8]);
            #pragma unroll
            for (int nf = 0; nf < 4; ++nf)
                s[nf] = MFMA16(qfr[ks], bk[nf], s[nf]);
        }
        if (k0 + 63 > qbase) {            // diagonal region: causal mask
            #pragma unroll
            for (int nf = 0; nf < 4; ++nf)
                #pragma unroll
                for (int r = 0; r < 4; ++r) {
                    const int ql = qbase + fq*4 + r;
                    const int kl = k0 + nf*16 + fr;
                    if (kl > ql) s[nf][r] = -1e30f;
                }
        }

        // online softmax (rows live in 16-lane groups; reduce over fr bits)
        float scale_[4];
        #pragma unroll
        for (int r = 0; r < 4; ++r) {
            float pm = fmaxf(fmaxf(s[0][r], s[1][r]), fmaxf(s[2][r], s[3][r]));
            pm = fmaxf(pm, __shfl_xor(pm, 1));
            pm = fmaxf(pm, __shfl_xor(pm, 2));
            pm = fmaxf(pm, __shfl_xor(pm, 4));
            pm = fmaxf(pm, __shfl_xor(pm, 8));
            const float mnew = fmaxf(m_run[r], pm);
            scale_[r] = __expf(m_run[r] - mnew);
            m_run[r] = mnew;
        }
        float rs[4] = {0.f,0.f,0.f,0.f};
        #pragma unroll
        for (int nf = 0; nf < 4; ++nf)
            #pragma unroll
            for (int r = 0; r < 4; ++r) {
                const float p = __expf(s[nf][r] - m_run[r]);
                rs[r] += p;
                Ps[w*16 + fq*4 + r][nf*16 + fr] = f2bfu(p);
            }
        #pragma unroll
        for (int r = 0; r < 4; ++r) {
            float v = rs[r];
            v += __shfl_xor(v, 1);
            v += __shfl_xor(v, 2);
            v += __shfl_xor(v, 4);
            v += __shfl_xor(v, 8);
            l_run[r] = l_run[r] * scale_[r] + v;
        }
        #pragma unroll
        for (int df = 0; df < 4; ++df)
            #pragma unroll
            for (int r = 0; r < 4; ++r)
                o[df][r] *= scale_[r];

        // O += P V  (Ps rows wave-private; same-wave LDS write->read)
        #pragma unroll
        for (int ks = 0; ks < 2; ++ks) {
            bf16x8 bv[4];
            #pragma unroll
            for (int df = 0; df < 4; ++df)
                bv[df] = *reinterpret_cast<const bf16x8*>(&Vt[df*16 + fr][ks*32 + fq*8]);
            bf16x8 apv = *reinterpret_cast<const bf16x8*>(&Ps[w*16 + fr][ks*32 + fq*8]);
            #pragma unroll
            for (int df = 0; df < 4; ++df)
                o[df] = MFMA16(apv, bv[df], o[df]);
        }
    }

    const int b = bh >> 4, h = bh & 15;
    #pragma unroll
    for (int r = 0; r < 4; ++r) {
        const int q = qbase + fq*4 + r;
        const float inv = 1.0f / l_run[r];
        #pragma unroll
        for (int df = 0; df < 4; ++df)
            attn_out[((size_t)(b*N_ + q))*E_ + h*64 + df*16 + fr] =
                f2bfu(o[df][r] * inv);
    }
}

// ---------------------------------------------------------------------------
// Kernel 3: out = attn @ Wo^T + bo (A bf16, B bf16 prepass), 2-phase prefetch.
// ---------------------------------------------------------------------------
__global__ __launch_bounds__(256) void out_mfma_kernel(
    const unsigned short* __restrict__ A, const unsigned short* __restrict__ Wobf,
    const float* __restrict__ bo, float* __restrict__ out)
{
    const int m0 = blockIdx.y * 128;
    const int n0 = blockIdx.x * 128;
    __shared__ unsigned short As[128][72];
    __shared__ unsigned short Bs[128][72];
    const int t = threadIdx.x;
    const int lane = t & 63;
    const int w = t >> 6, wr = w >> 1, wc = w & 1;
    const int fr = lane & 15, fq = lane >> 4;
    const int srow = t >> 1, scol = (t & 1) * 32;
    f32x4 acc[4][4] = {};

    const unsigned short* arow = A + (size_t)(m0 + srow) * E_ + scol;
    const unsigned short* brow = Wobf + (size_t)(n0 + srow) * E_ + scol;

    u16x8 a8[4], b8[4];
    #pragma unroll
    for (int i = 0; i < 4; ++i) a8[i] = reinterpret_cast<const u16x8*>(arow)[i];
    #pragma unroll
    for (int i = 0; i < 4; ++i) b8[i] = reinterpret_cast<const u16x8*>(brow)[i];

    for (int k0 = 0; k0 < E_; k0 += 64) {
        __syncthreads();
        #pragma unroll
        for (int j = 0; j < 4; ++j) {
            *reinterpret_cast<u16x8*>(&As[srow][scol + 8*j]) = a8[j];
            *reinterpret_cast<u16x8*>(&Bs[srow][scol + 8*j]) = b8[j];
        }
        __syncthreads();
        if (k0 + 64 < E_) {
            #pragma unroll
            for (int i = 0; i < 4; ++i)
                a8[i] = reinterpret_cast<const u16x8*>(arow + k0 + 64)[i];
            #pragma unroll
            for (int i = 0; i < 4; ++i)
                b8[i] = reinterpret_cast<const u16x8*>(brow + k0 + 64)[i];
        }
        #pragma unroll
        for (int ks = 0; ks < 2; ++ks) {
            bf16x8 af[4], bfv[4];
            #pragma unroll
            for (int mf = 0; mf < 4; ++mf)
                af[mf] = *reinterpret_cast<const bf16x8*>(&As[wr*64 + mf*16 + fr][ks*32 + fq*8]);
            #pragma unroll
            for (int nf = 0; nf < 4; ++nf)
                bfv[nf] = *reinterpret_cast<const bf16x8*>(&Bs[wc*64 + nf*16 + fr][ks*32 + fq*8]);
            #pragma unroll
            for (int mf = 0; mf < 4; ++mf)
                #pragma unroll
                for (int nf = 0; nf < 4; ++nf)
                    acc[mf][nf] = MFMA16(af[mf], bfv[nf], acc[mf][nf]);
        }
    }

    #pragma unroll
    for (int mf = 0; mf < 4; ++mf) {
        #pragma unroll
        for (int r = 0; r < 4; ++r) {
            const int m = m0 + wr*64 + mf*16 + fq*4 + r;
            #pragma unroll
            for (int nf = 0; nf < 4; ++nf) {
                const int n = n0 + wc*64 + nf*16 + fr;
                out[(size_t)m * E_ + n] = acc[mf][nf][r] + bo[n];
            }
        }
    }
}

extern "C" void kernel_launch(void* const* d_in, const int* in_sizes, int n_in,
                              void* d_out, int out_size, void* d_ws, size_t ws_size,
                              hipStream_t stream) {
    const float* x  = (const float*)d_in[0];
    // d_in[1] = mask (causal tril, applied analytically)
    const float* Wq = (const float*)d_in[2];
    const float* Wk = (const float*)d_in[3];
    const float* Wv = (const float*)d_in[4];
    const float* Wo = (const float*)d_in[5];
    const float* bo = (const float*)d_in[6];
    float* out = (float*)d_out;

    // ws layout (u16 units), 4 regions of M_*E_:
    //   region0: Wbf(q,k,v) -> later attn_out
    //   region1: Q          -> later Wo-bf16 (Q dead after attn)
    //   region2: K
    //   region3: V^T
    unsigned short* ws = (unsigned short*)d_ws;
    unsigned short* wbf = ws;
    unsigned short* attn_ws = ws;
    unsigned short* wobf = ws + (size_t)M_ * E_;

    const int cgrid = E_ * E_ / (256 * 8);
    fconv_kernel<<<cgrid, 256, 0, stream>>>(Wq, wbf);
    fconv_kernel<<<cgrid, 256, 0, stream>>>(Wk, wbf + (size_t)E_ * E_);
    fconv_kernel<<<cgrid, 256, 0, stream>>>(Wv, wbf + 2 * (size_t)E_ * E_);

    dim3 g1(E_ / 128, M_ / 128, 3);
    qkv_mfma_kernel<<<g1, 256, 0, stream>>>(x, wbf, ws);

    dim3 g2(16, B_ * H_);
    attn_mfma_kernel<<<g2, 512, 0, stream>>>(ws, attn_ws);

    fconv_kernel<<<cgrid, 256, 0, stream>>>(Wo, wobf);

    dim3 g3(E_ / 128, M_ / 128);
    out_mfma_kernel<<<g3, 256, 0, stream>>>(attn_ws, wobf, bo, out);
}

// Round 7
// 137.262 us; speedup vs baseline: 9.8711x; 1.3223x over previous
//
#include <hip/hip_runtime.h>
#include <hip/hip_bf16.h>

#define B_  2
#define N_  2048
#define E_  1024
#define H_  16
#define HD_ 64
#define M_  (B_*N_)
#define RSZ ((size_t)M_ * E_)          // one ws region, u16 elems (8 MB)

typedef short bf16x8 __attribute__((ext_vector_type(8)));
typedef float f32x4 __attribute__((ext_vector_type(4)));
typedef unsigned short u16x8 __attribute__((ext_vector_type(8)));

__device__ __forceinline__ unsigned short f2bfu(float f) {
    __hip_bfloat16 h = __float2bfloat16(f);
    return *reinterpret_cast<unsigned short*>(&h);
}
#define MFMA16(a,b,c) __builtin_amdgcn_mfma_f32_16x16x32_bf16((a),(b),(c),0,0,0)

// ---------------------------------------------------------------------------
// Kernel 0a: fused fp32->bf16 conversion for x + Wq,Wk,Wv,Wo in ONE launch.
// bid [0,2048): x (4M elems). bid [2048+512z, 2048+512(z+1)): W_z -> wbf+z*E*E.
// ---------------------------------------------------------------------------
__global__ __launch_bounds__(256) void fconv_all_kernel(
    const float* __restrict__ x,
    const float* __restrict__ Wq, const float* __restrict__ Wk,
    const float* __restrict__ Wv, const float* __restrict__ Wo,
    unsigned short* __restrict__ xbf, unsigned short* __restrict__ wbf)
{
    const int bid = blockIdx.x;
    const float* src;
    unsigned short* dst;
    int off;
    if (bid < 2048) {
        src = x; dst = xbf; off = bid * 2048 + threadIdx.x * 8;
    } else {
        const int z = (bid - 2048) >> 9;             // 0..3
        src = (z == 0) ? Wq : (z == 1 ? Wk : (z == 2 ? Wv : Wo));
        dst = wbf + (size_t)z * E_ * E_;
        off = ((bid - 2048) & 511) * 2048 + threadIdx.x * 8;
    }
    const float4 a = *reinterpret_cast<const float4*>(src + off);
    const float4 b = *reinterpret_cast<const float4*>(src + off + 4);
    u16x8 v;
    v[0]=f2bfu(a.x); v[1]=f2bfu(a.y); v[2]=f2bfu(a.z); v[3]=f2bfu(a.w);
    v[4]=f2bfu(b.x); v[5]=f2bfu(b.y); v[6]=f2bfu(b.z); v[7]=f2bfu(b.w);
    *reinterpret_cast<u16x8*>(dst + off) = v;
}

// Kernel 0b: single-source conversion (fallback path only)
__global__ __launch_bounds__(256) void fconv_kernel(
    const float* __restrict__ src, unsigned short* __restrict__ dst)
{
    const int i0 = (blockIdx.x * 256 + threadIdx.x) * 8;
    const float4 a = *reinterpret_cast<const float4*>(src + i0);
    const float4 b = *reinterpret_cast<const float4*>(src + i0 + 4);
    u16x8 v;
    v[0]=f2bfu(a.x); v[1]=f2bfu(a.y); v[2]=f2bfu(a.z); v[3]=f2bfu(a.w);
    v[4]=f2bfu(b.x); v[5]=f2bfu(b.y); v[6]=f2bfu(b.z); v[7]=f2bfu(b.w);
    *reinterpret_cast<u16x8*>(dst + i0) = v;
}

// ---------------------------------------------------------------------------
// Kernel 1a (main): QKV projection, all-bf16 operands, 2-phase prefetch.
// Grid (m=32, n=8, z=3): m fastest => all n-blocks of one m-tile land on the
// same XCD (id%8 == m%8) -> x tile served from that XCD's L2.
// z==2 writes V^T [bh][64 d][2048 n]. Q pre-scaled by 1/8.
// ---------------------------------------------------------------------------
__global__ __launch_bounds__(256) void qkv_bf_kernel(
    const unsigned short* __restrict__ xbf, const unsigned short* __restrict__ wbf,
    unsigned short* __restrict__ qkv)
{
    const int z = blockIdx.z;
    const unsigned short* __restrict__ W = wbf + (size_t)z * E_ * E_;
    unsigned short* __restrict__ out = qkv + (size_t)z * RSZ;
    const int m0 = blockIdx.x * 128;
    const int n0 = blockIdx.y * 128;
    __shared__ unsigned short As[128][72];
    __shared__ unsigned short Bs[128][72];
    const int t = threadIdx.x;
    const int lane = t & 63;
    const int w = t >> 6, wr = w >> 1, wc = w & 1;
    const int fr = lane & 15, fq = lane >> 4;
    const int srow = t >> 1, scol = (t & 1) * 32;
    f32x4 acc[4][4] = {};

    const unsigned short* arow = xbf + (size_t)(m0 + srow) * E_ + scol;
    const unsigned short* brow = W + (size_t)(n0 + srow) * E_ + scol;

    u16x8 a8[4], b8[4];
    #pragma unroll
    for (int i = 0; i < 4; ++i) a8[i] = reinterpret_cast<const u16x8*>(arow)[i];
    #pragma unroll
    for (int i = 0; i < 4; ++i) b8[i] = reinterpret_cast<const u16x8*>(brow)[i];

    for (int k0 = 0; k0 < E_; k0 += 64) {
        __syncthreads();
        #pragma unroll
        for (int j = 0; j < 4; ++j) {
            *reinterpret_cast<u16x8*>(&As[srow][scol + 8*j]) = a8[j];
            *reinterpret_cast<u16x8*>(&Bs[srow][scol + 8*j]) = b8[j];
        }
        __syncthreads();
        if (k0 + 64 < E_) {
            #pragma unroll
            for (int i = 0; i < 4; ++i)
                a8[i] = reinterpret_cast<const u16x8*>(arow + k0 + 64)[i];
            #pragma unroll
            for (int i = 0; i < 4; ++i)
                b8[i] = reinterpret_cast<const u16x8*>(brow + k0 + 64)[i];
        }
        #pragma unroll
        for (int ks = 0; ks < 2; ++ks) {
            bf16x8 af[4], bfv[4];
            #pragma unroll
            for (int mf = 0; mf < 4; ++mf)
                af[mf] = *reinterpret_cast<const bf16x8*>(&As[wr*64 + mf*16 + fr][ks*32 + fq*8]);
            #pragma unroll
            for (int nf = 0; nf < 4; ++nf)
                bfv[nf] = *reinterpret_cast<const bf16x8*>(&Bs[wc*64 + nf*16 + fr][ks*32 + fq*8]);
            #pragma unroll
            for (int mf = 0; mf < 4; ++mf)
                #pragma unroll
                for (int nf = 0; nf < 4; ++nf)
                    acc[mf][nf] = MFMA16(af[mf], bfv[nf], acc[mf][nf]);
        }
    }

    const float scale = (z == 0) ? 0.125f : 1.0f;
    #pragma unroll
    for (int mf = 0; mf < 4; ++mf) {
        #pragma unroll
        for (int r = 0; r < 4; ++r) {
            const int m = m0 + wr*64 + mf*16 + fq*4 + r;
            const int b = m >> 11, npos = m & (N_ - 1);
            #pragma unroll
            for (int nf = 0; nf < 4; ++nf) {
                const int n = n0 + wc*64 + nf*16 + fr;
                const int h = n >> 6, d = n & 63;
                const unsigned short val = f2bfu(acc[mf][nf][r] * scale);
                if (z == 2)   // V^T: [bh][d][npos]
                    out[(((size_t)(b*H_ + h))*HD_ + d)*N_ + npos] = val;
                else
                    out[(((size_t)(b*H_ + h))*N_ + npos)*HD_ + d] = val;
            }
        }
    }
}

// ---------------------------------------------------------------------------
// Kernel 1b (fallback): QKV with fp32 x converted at staging (R6-proven),
// same XCD-locality grid order.
// ---------------------------------------------------------------------------
__global__ __launch_bounds__(256) void qkv_f32_kernel(
    const float* __restrict__ x, const unsigned short* __restrict__ wbf,
    unsigned short* __restrict__ qkv)
{
    const int z = blockIdx.z;
    const unsigned short* __restrict__ W = wbf + (size_t)z * E_ * E_;
    unsigned short* __restrict__ out = qkv + (size_t)z * RSZ;
    const int m0 = blockIdx.x * 128;
    const int n0 = blockIdx.y * 128;
    __shared__ unsigned short As[128][72];
    __shared__ unsigned short Bs[128][72];
    const int t = threadIdx.x;
    const int lane = t & 63;
    const int w = t >> 6, wr = w >> 1, wc = w & 1;
    const int fr = lane & 15, fq = lane >> 4;
    const int srow = t >> 1, scol = (t & 1) * 32;
    f32x4 acc[4][4] = {};

    const float* arow = x + (size_t)(m0 + srow) * E_ + scol;
    const unsigned short* brow = W + (size_t)(n0 + srow) * E_ + scol;

    float4 a4[8];
    u16x8 b8[4];
    #pragma unroll
    for (int i = 0; i < 8; ++i) a4[i] = reinterpret_cast<const float4*>(arow)[i];
    #pragma unroll
    for (int i = 0; i < 4; ++i) b8[i] = reinterpret_cast<const u16x8*>(brow)[i];

    for (int k0 = 0; k0 < E_; k0 += 64) {
        __syncthreads();
        #pragma unroll
        for (int j = 0; j < 4; ++j) {
            u16x8 va;
            va[0]=f2bfu(a4[2*j].x); va[1]=f2bfu(a4[2*j].y); va[2]=f2bfu(a4[2*j].z); va[3]=f2bfu(a4[2*j].w);
            va[4]=f2bfu(a4[2*j+1].x); va[5]=f2bfu(a4[2*j+1].y); va[6]=f2bfu(a4[2*j+1].z); va[7]=f2bfu(a4[2*j+1].w);
            *reinterpret_cast<u16x8*>(&As[srow][scol + 8*j]) = va;
            *reinterpret_cast<u16x8*>(&Bs[srow][scol + 8*j]) = b8[j];
        }
        __syncthreads();
        if (k0 + 64 < E_) {
            #pragma unroll
            for (int i = 0; i < 8; ++i)
                a4[i] = reinterpret_cast<const float4*>(arow + k0 + 64)[i];
            #pragma unroll
            for (int i = 0; i < 4; ++i)
                b8[i] = reinterpret_cast<const u16x8*>(brow + k0 + 64)[i];
        }
        #pragma unroll
        for (int ks = 0; ks < 2; ++ks) {
            bf16x8 af[4], bfv[4];
            #pragma unroll
            for (int mf = 0; mf < 4; ++mf)
                af[mf] = *reinterpret_cast<const bf16x8*>(&As[wr*64 + mf*16 + fr][ks*32 + fq*8]);
            #pragma unroll
            for (int nf = 0; nf < 4; ++nf)
                bfv[nf] = *reinterpret_cast<const bf16x8*>(&Bs[wc*64 + nf*16 + fr][ks*32 + fq*8]);
            #pragma unroll
            for (int mf = 0; mf < 4; ++mf)
                #pragma unroll
                for (int nf = 0; nf < 4; ++nf)
                    acc[mf][nf] = MFMA16(af[mf], bfv[nf], acc[mf][nf]);
        }
    }

    const float scale = (z == 0) ? 0.125f : 1.0f;
    #pragma unroll
    for (int mf = 0; mf < 4; ++mf) {
        #pragma unroll
        for (int r = 0; r < 4; ++r) {
            const int m = m0 + wr*64 + mf*16 + fq*4 + r;
            const int b = m >> 11, npos = m & (N_ - 1);
            #pragma unroll
            for (int nf = 0; nf < 4; ++nf) {
                const int n = n0 + wc*64 + nf*16 + fr;
                const int h = n >> 6, d = n & 63;
                const unsigned short val = f2bfu(acc[mf][nf][r] * scale);
                if (z == 2)
                    out[(((size_t)(b*H_ + h))*HD_ + d)*N_ + npos] = val;
                else
                    out[(((size_t)(b*H_ + h))*N_ + npos)*HD_ + d] = val;
            }
        }
    }
}

// ---------------------------------------------------------------------------
// Kernel 2: MFMA flash attention (R6-proven). 512 thr / 8 waves; 16 q-rows
// per wave; pair (heavy=31-xp, light=xp); shared K/V staging; reg prefetch.
// Q/K/Vt base pointers parameterized (layout differs between paths).
// ---------------------------------------------------------------------------
__global__ __launch_bounds__(512) void attn_mfma_kernel(
    const unsigned short* __restrict__ qkv, unsigned short* __restrict__ attn_out)
{
    const int xp = blockIdx.x;            // 0..15
    const int bh = blockIdx.y;            // 0..31
    const unsigned short* Qp  = qkv + (size_t)bh * N_ * HD_;
    const unsigned short* Kp  = qkv + RSZ + (size_t)bh * N_ * HD_;
    const unsigned short* Vtp = qkv + 2*RSZ + (size_t)bh * N_ * HD_;
    __shared__ unsigned short Ks[64][72], Vt[64][72], Ps[128][76];
    const int t = threadIdx.x;
    const int lane = t & 63, w = t >> 6;
    const int fr = lane & 15, fq = lane >> 4;
    const int srow = t >> 3, sc0 = (t & 7) * 8;
    const int qbase = (w < 4) ? ((31 - xp) * 64 + w * 16)
                              : (xp * 64 + (w - 4) * 16);
    const int KT = 32 - xp;               // heavy tile's k-range (superset)

    bf16x8 qfr[2];
    #pragma unroll
    for (int ks = 0; ks < 2; ++ks)
        qfr[ks] = *reinterpret_cast<const bf16x8*>(
            Qp + (size_t)(qbase + fr) * HD_ + ks*32 + fq*8);

    float m_run[4], l_run[4];
    #pragma unroll
    for (int i = 0; i < 4; ++i) { m_run[i] = -1e30f; l_run[i] = 0.f; }
    f32x4 o[4] = {};

    u16x8 kreg = *reinterpret_cast<const u16x8*>(Kp + (size_t)srow * HD_ + sc0);
    u16x8 vreg = *reinterpret_cast<const u16x8*>(Vtp + (size_t)srow * N_ + sc0);

    for (int kt = 0; kt < KT; ++kt) {
        const int k0 = kt * 64;
        __syncthreads();
        *reinterpret_cast<u16x8*>(&Ks[srow][sc0]) = kreg;
        *reinterpret_cast<u16x8*>(&Vt[srow][sc0]) = vreg;
        __syncthreads();
        if (kt + 1 < KT) {
            kreg = *reinterpret_cast<const u16x8*>(Kp + (size_t)(k0 + 64 + srow) * HD_ + sc0);
            vreg = *reinterpret_cast<const u16x8*>(Vtp + (size_t)srow * N_ + k0 + 64 + sc0);
        }
        if (k0 > qbase + 15) continue;

        f32x4 s[4] = {};
        #pragma unroll
        for (int ks = 0; ks < 2; ++ks) {
            bf16x8 bk[4];
            #pragma unroll
            for (int nf = 0; nf < 4; ++nf)
                bk[nf] = *reinterpret_cast<const bf16x8*>(&Ks[nf*16 + fr][ks*32 + fq*8]);
            #pragma unroll
            for (int nf = 0; nf < 4; ++nf)
                s[nf] = MFMA16(qfr[ks], bk[nf], s[nf]);
        }
        if (k0 + 63 > qbase) {
            #pragma unroll
            for (int nf = 0; nf < 4; ++nf)
                #pragma unroll
                for (int r = 0; r < 4; ++r) {
                    const int ql = qbase + fq*4 + r;
                    const int kl = k0 + nf*16 + fr;
                    if (kl > ql) s[nf][r] = -1e30f;
                }
        }

        float scale_[4];
        #pragma unroll
        for (int r = 0; r < 4; ++r) {
            float pm = fmaxf(fmaxf(s[0][r], s[1][r]), fmaxf(s[2][r], s[3][r]));
            pm = fmaxf(pm, __shfl_xor(pm, 1));
            pm = fmaxf(pm, __shfl_xor(pm, 2));
            pm = fmaxf(pm, __shfl_xor(pm, 4));
            pm = fmaxf(pm, __shfl_xor(pm, 8));
            const float mnew = fmaxf(m_run[r], pm);
            scale_[r] = __expf(m_run[r] - mnew);
            m_run[r] = mnew;
        }
        float rs[4] = {0.f,0.f,0.f,0.f};
        #pragma unroll
        for (int nf = 0; nf < 4; ++nf)
            #pragma unroll
            for (int r = 0; r < 4; ++r) {
                const float p = __expf(s[nf][r] - m_run[r]);
                rs[r] += p;
                Ps[w*16 + fq*4 + r][nf*16 + fr] = f2bfu(p);
            }
        #pragma unroll
        for (int r = 0; r < 4; ++r) {
            float v = rs[r];
            v += __shfl_xor(v, 1);
            v += __shfl_xor(v, 2);
            v += __shfl_xor(v, 4);
            v += __shfl_xor(v, 8);
            l_run[r] = l_run[r] * scale_[r] + v;
        }
        #pragma unroll
        for (int df = 0; df < 4; ++df)
            #pragma unroll
            for (int r = 0; r < 4; ++r)
                o[df][r] *= scale_[r];

        #pragma unroll
        for (int ks = 0; ks < 2; ++ks) {
            bf16x8 bv[4];
            #pragma unroll
            for (int df = 0; df < 4; ++df)
                bv[df] = *reinterpret_cast<const bf16x8*>(&Vt[df*16 + fr][ks*32 + fq*8]);
            bf16x8 apv = *reinterpret_cast<const bf16x8*>(&Ps[w*16 + fr][ks*32 + fq*8]);
            #pragma unroll
            for (int df = 0; df < 4; ++df)
                o[df] = MFMA16(apv, bv[df], o[df]);
        }
    }

    const int b = bh >> 4, h = bh & 15;
    #pragma unroll
    for (int r = 0; r < 4; ++r) {
        const int q = qbase + fq*4 + r;
        const float inv = 1.0f / l_run[r];
        #pragma unroll
        for (int df = 0; df < 4; ++df)
            attn_out[((size_t)(b*N_ + q))*E_ + h*64 + df*16 + fr] =
                f2bfu(o[df][r] * inv);
    }
}

// ---------------------------------------------------------------------------
// Kernel 3: out = attn @ Wo^T + bo (all-bf16 staging, 2-phase prefetch,
// XCD-locality grid: m fastest).
// ---------------------------------------------------------------------------
__global__ __launch_bounds__(256) void out_mfma_kernel(
    const unsigned short* __restrict__ A, const unsigned short* __restrict__ Wobf,
    const float* __restrict__ bo, float* __restrict__ out)
{
    const int m0 = blockIdx.x * 128;
    const int n0 = blockIdx.y * 128;
    __shared__ unsigned short As[128][72];
    __shared__ unsigned short Bs[128][72];
    const int t = threadIdx.x;
    const int lane = t & 63;
    const int w = t >> 6, wr = w >> 1, wc = w & 1;
    const int fr = lane & 15, fq = lane >> 4;
    const int srow = t >> 1, scol = (t & 1) * 32;
    f32x4 acc[4][4] = {};

    const unsigned short* arow = A + (size_t)(m0 + srow) * E_ + scol;
    const unsigned short* brow = Wobf + (size_t)(n0 + srow) * E_ + scol;

    u16x8 a8[4], b8[4];
    #pragma unroll
    for (int i = 0; i < 4; ++i) a8[i] = reinterpret_cast<const u16x8*>(arow)[i];
    #pragma unroll
    for (int i = 0; i < 4; ++i) b8[i] = reinterpret_cast<const u16x8*>(brow)[i];

    for (int k0 = 0; k0 < E_; k0 += 64) {
        __syncthreads();
        #pragma unroll
        for (int j = 0; j < 4; ++j) {
            *reinterpret_cast<u16x8*>(&As[srow][scol + 8*j]) = a8[j];
            *reinterpret_cast<u16x8*>(&Bs[srow][scol + 8*j]) = b8[j];
        }
        __syncthreads();
        if (k0 + 64 < E_) {
            #pragma unroll
            for (int i = 0; i < 4; ++i)
                a8[i] = reinterpret_cast<const u16x8*>(arow + k0 + 64)[i];
            #pragma unroll
            for (int i = 0; i < 4; ++i)
                b8[i] = reinterpret_cast<const u16x8*>(brow + k0 + 64)[i];
        }
        #pragma unroll
        for (int ks = 0; ks < 2; ++ks) {
            bf16x8 af[4], bfv[4];
            #pragma unroll
            for (int mf = 0; mf < 4; ++mf)
                af[mf] = *reinterpret_cast<const bf16x8*>(&As[wr*64 + mf*16 + fr][ks*32 + fq*8]);
            #pragma unroll
            for (int nf = 0; nf < 4; ++nf)
                bfv[nf] = *reinterpret_cast<const bf16x8*>(&Bs[wc*64 + nf*16 + fr][ks*32 + fq*8]);
            #pragma unroll
            for (int mf = 0; mf < 4; ++mf)
                #pragma unroll
                for (int nf = 0; nf < 4; ++nf)
                    acc[mf][nf] = MFMA16(af[mf], bfv[nf], acc[mf][nf]);
        }
    }

    #pragma unroll
    for (int mf = 0; mf < 4; ++mf) {
        #pragma unroll
        for (int r = 0; r < 4; ++r) {
            const int m = m0 + wr*64 + mf*16 + fq*4 + r;
            #pragma unroll
            for (int nf = 0; nf < 4; ++nf) {
                const int n = n0 + wc*64 + nf*16 + fr;
                out[(size_t)m * E_ + n] = acc[mf][nf][r] + bo[n];
            }
        }
    }
}

extern "C" void kernel_launch(void* const* d_in, const int* in_sizes, int n_in,
                              void* d_out, int out_size, void* d_ws, size_t ws_size,
                              hipStream_t stream) {
    const float* x  = (const float*)d_in[0];
    // d_in[1] = mask (causal tril, applied analytically)
    const float* Wq = (const float*)d_in[2];
    const float* Wk = (const float*)d_in[3];
    const float* Wv = (const float*)d_in[4];
    const float* Wo = (const float*)d_in[5];
    const float* bo = (const float*)d_in[6];
    float* out = (float*)d_out;

    unsigned short* ws = (unsigned short*)d_ws;
    const size_t need_main = 5 * RSZ * sizeof(unsigned short);   // 40 MB

    if (ws_size >= need_main) {
        // layout: A=xbf(8MB)->attn_out, B=wbf(Wq,Wk,Wv,Wo; 8MB),
        //         C=Q, D=K, E=Vt
        unsigned short* xbf  = ws;
        unsigned short* wbf  = ws + RSZ;
        unsigned short* qkvq = ws + 2 * RSZ;          // Q,K,Vt contiguous
        unsigned short* attn_ws = ws;                 // over xbf (dead)
        unsigned short* wobf = wbf + 3 * (size_t)E_ * E_;

        fconv_all_kernel<<<4096, 256, 0, stream>>>(x, Wq, Wk, Wv, Wo, xbf, wbf);

        dim3 g1(M_ / 128, E_ / 128, 3);               // m fastest: XCD locality
        qkv_bf_kernel<<<g1, 256, 0, stream>>>(xbf, wbf, qkvq);

        dim3 g2(16, B_ * H_);
        attn_mfma_kernel<<<g2, 512, 0, stream>>>(qkvq, attn_ws);

        dim3 g3(M_ / 128, E_ / 128);
        out_mfma_kernel<<<g3, 256, 0, stream>>>(attn_ws, wobf, bo, out);
    } else {
        // fallback (R6 layout): region0=wbf->attn_out, 1=Q->wobf, 2=K, 3=Vt
        unsigned short* wbf = ws;
        unsigned short* qkvq = ws + RSZ;
        unsigned short* attn_ws = ws;
        unsigned short* wobf = ws + RSZ;

        const int cgrid = E_ * E_ / (256 * 8);
        fconv_kernel<<<cgrid, 256, 0, stream>>>(Wq, wbf);
        fconv_kernel<<<cgrid, 256, 0, stream>>>(Wk, wbf + (size_t)E_ * E_);
        fconv_kernel<<<cgrid, 256, 0, stream>>>(Wv, wbf + 2 * (size_t)E_ * E_);

        dim3 g1(M_ / 128, E_ / 128, 3);
        qkv_f32_kernel<<<g1, 256, 0, stream>>>(x, wbf, qkvq);

        dim3 g2(16, B_ * H_);
        attn_mfma_kernel<<<g2, 512, 0, stream>>>(qkvq, attn_ws);

        fconv_kernel<<<cgrid, 256, 0, stream>>>(Wo, wobf);

        dim3 g3(M_ / 128, E_ / 128);
        out_mfma_kernel<<<g3, 256, 0, stream>>>(attn_ws, wobf, bo, out);
    }
}

// Round 8
// 118.064 us; speedup vs baseline: 11.4762x; 1.1626x over previous
//
#include <hip/hip_runtime.h>
#include <hip/hip_bf16.h>

#define B_  2
#define N_  2048
#define E_  1024
#define H_  16
#define HD_ 64
#define M_  (B_*N_)
#define RSZ ((size_t)M_ * E_)          // one ws region, u16 elems (8 MB)

typedef short bf16x8 __attribute__((ext_vector_type(8)));
typedef float f32x4 __attribute__((ext_vector_type(4)));
typedef unsigned short u16x8 __attribute__((ext_vector_type(8)));

__device__ __forceinline__ unsigned short f2bfu(float f) {
    __hip_bfloat16 h = __float2bfloat16(f);
    return *reinterpret_cast<unsigned short*>(&h);
}
__device__ __forceinline__ unsigned int pack2bf(float lo, float hi) {
    return ((unsigned int)f2bfu(hi) << 16) | (unsigned int)f2bfu(lo);
}
#define MFMA16(a,b,c) __builtin_amdgcn_mfma_f32_16x16x32_bf16((a),(b),(c),0,0,0)

// ---------------------------------------------------------------------------
// Kernel 0a: fused fp32->bf16 conversion for x + Wq,Wk,Wv,Wo in ONE launch.
// ---------------------------------------------------------------------------
__global__ __launch_bounds__(256) void fconv_all_kernel(
    const float* __restrict__ x,
    const float* __restrict__ Wq, const float* __restrict__ Wk,
    const float* __restrict__ Wv, const float* __restrict__ Wo,
    unsigned short* __restrict__ xbf, unsigned short* __restrict__ wbf)
{
    const int bid = blockIdx.x;
    const float* src;
    unsigned short* dst;
    int off;
    if (bid < 2048) {
        src = x; dst = xbf; off = bid * 2048 + threadIdx.x * 8;
    } else {
        const int z = (bid - 2048) >> 9;             // 0..3
        src = (z == 0) ? Wq : (z == 1 ? Wk : (z == 2 ? Wv : Wo));
        dst = wbf + (size_t)z * E_ * E_;
        off = ((bid - 2048) & 511) * 2048 + threadIdx.x * 8;
    }
    const float4 a = *reinterpret_cast<const float4*>(src + off);
    const float4 b = *reinterpret_cast<const float4*>(src + off + 4);
    u16x8 v;
    v[0]=f2bfu(a.x); v[1]=f2bfu(a.y); v[2]=f2bfu(a.z); v[3]=f2bfu(a.w);
    v[4]=f2bfu(b.x); v[5]=f2bfu(b.y); v[6]=f2bfu(b.z); v[7]=f2bfu(b.w);
    *reinterpret_cast<u16x8*>(dst + off) = v;
}

// Kernel 0b: single-source conversion (fallback path only)
__global__ __launch_bounds__(256) void fconv_kernel(
    const float* __restrict__ src, unsigned short* __restrict__ dst)
{
    const int i0 = (blockIdx.x * 256 + threadIdx.x) * 8;
    const float4 a = *reinterpret_cast<const float4*>(src + i0);
    const float4 b = *reinterpret_cast<const float4*>(src + i0 + 4);
    u16x8 v;
    v[0]=f2bfu(a.x); v[1]=f2bfu(a.y); v[2]=f2bfu(a.z); v[3]=f2bfu(a.w);
    v[4]=f2bfu(b.x); v[5]=f2bfu(b.y); v[6]=f2bfu(b.z); v[7]=f2bfu(b.w);
    *reinterpret_cast<u16x8*>(dst + i0) = v;
}

// ---------------------------------------------------------------------------
// Kernel 1a (main): QKV projection, all-bf16 operands, 2-phase prefetch.
// Grid (m, n, z), m fastest: XCD locality on x. z==2 writes V^T.
// ---------------------------------------------------------------------------
__global__ __launch_bounds__(256) void qkv_bf_kernel(
    const unsigned short* __restrict__ xbf, const unsigned short* __restrict__ wbf,
    unsigned short* __restrict__ qkv)
{
    const int z = blockIdx.z;
    const unsigned short* __restrict__ W = wbf + (size_t)z * E_ * E_;
    unsigned short* __restrict__ out = qkv + (size_t)z * RSZ;
    const int m0 = blockIdx.x * 128;
    const int n0 = blockIdx.y * 128;
    __shared__ unsigned short As[128][72];
    __shared__ unsigned short Bs[128][72];
    const int t = threadIdx.x;
    const int lane = t & 63;
    const int w = t >> 6, wr = w >> 1, wc = w & 1;
    const int fr = lane & 15, fq = lane >> 4;
    const int srow = t >> 1, scol = (t & 1) * 32;
    f32x4 acc[4][4] = {};

    const unsigned short* arow = xbf + (size_t)(m0 + srow) * E_ + scol;
    const unsigned short* brow = W + (size_t)(n0 + srow) * E_ + scol;

    u16x8 a8[4], b8[4];
    #pragma unroll
    for (int i = 0; i < 4; ++i) a8[i] = reinterpret_cast<const u16x8*>(arow)[i];
    #pragma unroll
    for (int i = 0; i < 4; ++i) b8[i] = reinterpret_cast<const u16x8*>(brow)[i];

    for (int k0 = 0; k0 < E_; k0 += 64) {
        __syncthreads();
        #pragma unroll
        for (int j = 0; j < 4; ++j) {
            *reinterpret_cast<u16x8*>(&As[srow][scol + 8*j]) = a8[j];
            *reinterpret_cast<u16x8*>(&Bs[srow][scol + 8*j]) = b8[j];
        }
        __syncthreads();
        if (k0 + 64 < E_) {
            #pragma unroll
            for (int i = 0; i < 4; ++i)
                a8[i] = reinterpret_cast<const u16x8*>(arow + k0 + 64)[i];
            #pragma unroll
            for (int i = 0; i < 4; ++i)
                b8[i] = reinterpret_cast<const u16x8*>(brow + k0 + 64)[i];
        }
        #pragma unroll
        for (int ks = 0; ks < 2; ++ks) {
            bf16x8 af[4], bfv[4];
            #pragma unroll
            for (int mf = 0; mf < 4; ++mf)
                af[mf] = *reinterpret_cast<const bf16x8*>(&As[wr*64 + mf*16 + fr][ks*32 + fq*8]);
            #pragma unroll
            for (int nf = 0; nf < 4; ++nf)
                bfv[nf] = *reinterpret_cast<const bf16x8*>(&Bs[wc*64 + nf*16 + fr][ks*32 + fq*8]);
            #pragma unroll
            for (int mf = 0; mf < 4; ++mf)
                #pragma unroll
                for (int nf = 0; nf < 4; ++nf)
                    acc[mf][nf] = MFMA16(af[mf], bfv[nf], acc[mf][nf]);
        }
    }

    const float scale = (z == 0) ? 0.125f : 1.0f;
    #pragma unroll
    for (int mf = 0; mf < 4; ++mf) {
        #pragma unroll
        for (int r = 0; r < 4; ++r) {
            const int m = m0 + wr*64 + mf*16 + fq*4 + r;
            const int b = m >> 11, npos = m & (N_ - 1);
            #pragma unroll
            for (int nf = 0; nf < 4; ++nf) {
                const int n = n0 + wc*64 + nf*16 + fr;
                const int h = n >> 6, d = n & 63;
                const unsigned short val = f2bfu(acc[mf][nf][r] * scale);
                if (z == 2)   // V^T: [bh][d][npos]
                    out[(((size_t)(b*H_ + h))*HD_ + d)*N_ + npos] = val;
                else
                    out[(((size_t)(b*H_ + h))*N_ + npos)*HD_ + d] = val;
            }
        }
    }
}

// ---------------------------------------------------------------------------
// Kernel 1b (fallback): QKV with fp32 x converted at staging.
// ---------------------------------------------------------------------------
__global__ __launch_bounds__(256) void qkv_f32_kernel(
    const float* __restrict__ x, const unsigned short* __restrict__ wbf,
    unsigned short* __restrict__ qkv)
{
    const int z = blockIdx.z;
    const unsigned short* __restrict__ W = wbf + (size_t)z * E_ * E_;
    unsigned short* __restrict__ out = qkv + (size_t)z * RSZ;
    const int m0 = blockIdx.x * 128;
    const int n0 = blockIdx.y * 128;
    __shared__ unsigned short As[128][72];
    __shared__ unsigned short Bs[128][72];
    const int t = threadIdx.x;
    const int lane = t & 63;
    const int w = t >> 6, wr = w >> 1, wc = w & 1;
    const int fr = lane & 15, fq = lane >> 4;
    const int srow = t >> 1, scol = (t & 1) * 32;
    f32x4 acc[4][4] = {};

    const float* arow = x + (size_t)(m0 + srow) * E_ + scol;
    const unsigned short* brow = W + (size_t)(n0 + srow) * E_ + scol;

    float4 a4[8];
    u16x8 b8[4];
    #pragma unroll
    for (int i = 0; i < 8; ++i) a4[i] = reinterpret_cast<const float4*>(arow)[i];
    #pragma unroll
    for (int i = 0; i < 4; ++i) b8[i] = reinterpret_cast<const u16x8*>(brow)[i];

    for (int k0 = 0; k0 < E_; k0 += 64) {
        __syncthreads();
        #pragma unroll
        for (int j = 0; j < 4; ++j) {
            u16x8 va;
            va[0]=f2bfu(a4[2*j].x); va[1]=f2bfu(a4[2*j].y); va[2]=f2bfu(a4[2*j].z); va[3]=f2bfu(a4[2*j].w);
            va[4]=f2bfu(a4[2*j+1].x); va[5]=f2bfu(a4[2*j+1].y); va[6]=f2bfu(a4[2*j+1].z); va[7]=f2bfu(a4[2*j+1].w);
            *reinterpret_cast<u16x8*>(&As[srow][scol + 8*j]) = va;
            *reinterpret_cast<u16x8*>(&Bs[srow][scol + 8*j]) = b8[j];
        }
        __syncthreads();
        if (k0 + 64 < E_) {
            #pragma unroll
            for (int i = 0; i < 8; ++i)
                a4[i] = reinterpret_cast<const float4*>(arow + k0 + 64)[i];
            #pragma unroll
            for (int i = 0; i < 4; ++i)
                b8[i] = reinterpret_cast<const u16x8*>(brow + k0 + 64)[i];
        }
        #pragma unroll
        for (int ks = 0; ks < 2; ++ks) {
            bf16x8 af[4], bfv[4];
            #pragma unroll
            for (int mf = 0; mf < 4; ++mf)
                af[mf] = *reinterpret_cast<const bf16x8*>(&As[wr*64 + mf*16 + fr][ks*32 + fq*8]);
            #pragma unroll
            for (int nf = 0; nf < 4; ++nf)
                bfv[nf] = *reinterpret_cast<const bf16x8*>(&Bs[wc*64 + nf*16 + fr][ks*32 + fq*8]);
            #pragma unroll
            for (int mf = 0; mf < 4; ++mf)
                #pragma unroll
                for (int nf = 0; nf < 4; ++nf)
                    acc[mf][nf] = MFMA16(af[mf], bfv[nf], acc[mf][nf]);
        }
    }

    const float scale = (z == 0) ? 0.125f : 1.0f;
    #pragma unroll
    for (int mf = 0; mf < 4; ++mf) {
        #pragma unroll
        for (int r = 0; r < 4; ++r) {
            const int m = m0 + wr*64 + mf*16 + fq*4 + r;
            const int b = m >> 11, npos = m & (N_ - 1);
            #pragma unroll
            for (int nf = 0; nf < 4; ++nf) {
                const int n = n0 + wc*64 + nf*16 + fr;
                const int h = n >> 6, d = n & 63;
                const unsigned short val = f2bfu(acc[mf][nf][r] * scale);
                if (z == 2)
                    out[(((size_t)(b*H_ + h))*HD_ + d)*N_ + npos] = val;
                else
                    out[(((size_t)(b*H_ + h))*N_ + npos)*HD_ + d] = val;
            }
        }
    }
}

// ---------------------------------------------------------------------------
// Kernel 2: MFMA flash attention, SWAPPED QK^T (S^T = K·Q^T) so each lane
// owns ONE q-row (q = lane&15): softmax = 16 in-reg ops + 2 shfls; P stays
// in registers (16 bpermutes redistribute into the PV B-fragment layout).
// PV = mfma(V^T-frag, P^T-frag) -> O^T. Pair (heavy=31-xp, light=xp), shared
// K/V staging, reg prefetch, defer-max (THR=8), setprio around MFMA.
// Grid bh-major: same-bh blocks share an XCD's L2 for K/V.
// ---------------------------------------------------------------------------
__global__ __launch_bounds__(512) void attn_mfma_kernel(
    const unsigned short* __restrict__ qkv, unsigned short* __restrict__ attn_out)
{
    const int bh = blockIdx.x;            // 0..31 (fastest -> XCD locality)
    const int xp = blockIdx.y;            // 0..15
    const unsigned short* Qp  = qkv + (size_t)bh * N_ * HD_;
    const unsigned short* Kp  = qkv + RSZ + (size_t)bh * N_ * HD_;
    const unsigned short* Vtp = qkv + 2*RSZ + (size_t)bh * N_ * HD_;
    __shared__ unsigned short Ks[64][72], Vt[64][72];
    const int t = threadIdx.x;
    const int lane = t & 63, w = t >> 6;
    const int fr = lane & 15, fq = lane >> 4;
    const int srow = t >> 3, sc0 = (t & 7) * 8;
    const int qbase = (w < 4) ? ((31 - xp) * 64 + w * 16)
                              : (xp * 64 + (w - 4) * 16);
    const int KT = 32 - xp;               // heavy tile's k-range (superset)
    const int ql = qbase + fr;            // this lane's q row
    const int lane_b0 = (2 * (fq & 1)) * 16 + fr;   // P-transport sources
    const int lane_b1 = lane_b0 + 16;
    const bool hi_sel = (fq >> 1) != 0;

    bf16x8 qfr[2];
    #pragma unroll
    for (int ks = 0; ks < 2; ++ks)
        qfr[ks] = *reinterpret_cast<const bf16x8*>(
            Qp + (size_t)ql * HD_ + ks*32 + fq*8);

    float m_run = -1e30f, l_run = 0.f;
    f32x4 o[4] = {};

    u16x8 kreg = *reinterpret_cast<const u16x8*>(Kp + (size_t)srow * HD_ + sc0);
    u16x8 vreg = *reinterpret_cast<const u16x8*>(Vtp + (size_t)srow * N_ + sc0);

    for (int kt = 0; kt < KT; ++kt) {
        const int k0 = kt * 64;
        __syncthreads();                  // prev tile's LDS reads complete
        *reinterpret_cast<u16x8*>(&Ks[srow][sc0]) = kreg;
        *reinterpret_cast<u16x8*>(&Vt[srow][sc0]) = vreg;
        __syncthreads();                  // staged tile visible
        if (kt + 1 < KT) {                // prefetch next (hides under compute)
            kreg = *reinterpret_cast<const u16x8*>(Kp + (size_t)(k0 + 64 + srow) * HD_ + sc0);
            vreg = *reinterpret_cast<const u16x8*>(Vtp + (size_t)srow * N_ + k0 + 64 + sc0);
        }
        if (k0 > qbase + 15) continue;    // fully masked for this wave

        // S^T = K Q^T: lane holds s[nf][r] = S[q=ql][k = k0+nf*16+fq*4+r]
        f32x4 s[4] = {};
        __builtin_amdgcn_s_setprio(1);
        #pragma unroll
        for (int ks = 0; ks < 2; ++ks) {
            bf16x8 bk[4];
            #pragma unroll
            for (int nf = 0; nf < 4; ++nf)
                bk[nf] = *reinterpret_cast<const bf16x8*>(&Ks[nf*16 + fr][ks*32 + fq*8]);
            #pragma unroll
            for (int nf = 0; nf < 4; ++nf)
                s[nf] = MFMA16(bk[nf], qfr[ks], s[nf]);
        }
        __builtin_amdgcn_s_setprio(0);

        if (k0 + 63 > qbase) {            // diagonal region: causal mask
            #pragma unroll
            for (int nf = 0; nf < 4; ++nf)
                #pragma unroll
                for (int r = 0; r < 4; ++r)
                    if (k0 + nf*16 + fq*4 + r > ql) s[nf][r] = -1e30f;
        }

        // row max: 16 in-register + 2 shfls (over fq groups)
        float pm = -1e30f;
        #pragma unroll
        for (int nf = 0; nf < 4; ++nf)
            pm = fmaxf(pm, fmaxf(fmaxf(s[nf][0], s[nf][1]),
                                 fmaxf(s[nf][2], s[nf][3])));
        pm = fmaxf(pm, __shfl_xor(pm, 16));
        pm = fmaxf(pm, __shfl_xor(pm, 32));

        // defer-max (THR=8): rescale only when max grew materially
        const bool need = __any(pm > m_run + 8.f);
        float scl = 1.f;
        if (need) {
            const float mnew = fmaxf(m_run, pm);
            scl = __expf(m_run - mnew);
            m_run = mnew;
        }

        // P = exp(S - m), packed to bf16 pairs in-register
        float rs = 0.f;
        unsigned int u[4][2];
        #pragma unroll
        for (int nf = 0; nf < 4; ++nf) {
            const float p0 = __expf(s[nf][0] - m_run);
            const float p1 = __expf(s[nf][1] - m_run);
            const float p2 = __expf(s[nf][2] - m_run);
            const float p3 = __expf(s[nf][3] - m_run);
            rs += (p0 + p1) + (p2 + p3);
            u[nf][0] = pack2bf(p0, p1);
            u[nf][1] = pack2bf(p2, p3);
        }
        {
            float v = rs;
            v += __shfl_xor(v, 16);
            v += __shfl_xor(v, 32);
            l_run = l_run * scl + v;
        }
        if (need) {
            #pragma unroll
            for (int df = 0; df < 4; ++df)
                #pragma unroll
                for (int r = 0; r < 4; ++r)
                    o[df][r] *= scl;
        }

        // P-transport: build PV B-frags pb[ks] (k = ks*32 + fq*8 + 0..7)
        bf16x8 pb[2];
        #pragma unroll
        for (int ks = 0; ks < 2; ++ks) {
            const unsigned int t00 = __shfl(u[2*ks+0][0], lane_b0);
            const unsigned int t01 = __shfl(u[2*ks+0][1], lane_b0);
            const unsigned int t02 = __shfl(u[2*ks+0][0], lane_b1);
            const unsigned int t03 = __shfl(u[2*ks+0][1], lane_b1);
            const unsigned int t10 = __shfl(u[2*ks+1][0], lane_b0);
            const unsigned int t11 = __shfl(u[2*ks+1][1], lane_b0);
            const unsigned int t12 = __shfl(u[2*ks+1][0], lane_b1);
            const unsigned int t13 = __shfl(u[2*ks+1][1], lane_b1);
            union { unsigned int wd[4]; bf16x8 v; } pu;
            pu.wd[0] = hi_sel ? t10 : t00;
            pu.wd[1] = hi_sel ? t11 : t01;
            pu.wd[2] = hi_sel ? t12 : t02;
            pu.wd[3] = hi_sel ? t13 : t03;
            pb[ks] = pu.v;
        }

        // O^T += V^T P^T
        __builtin_amdgcn_s_setprio(1);
        #pragma unroll
        for (int ks = 0; ks < 2; ++ks) {
            bf16x8 bv[4];
            #pragma unroll
            for (int df = 0; df < 4; ++df)
                bv[df] = *reinterpret_cast<const bf16x8*>(&Vt[df*16 + fr][ks*32 + fq*8]);
            #pragma unroll
            for (int df = 0; df < 4; ++df)
                o[df] = MFMA16(bv[df], pb[ks], o[df]);
        }
        __builtin_amdgcn_s_setprio(0);
    }

    // epilogue: lane holds O^T[d][q=ql], d = df*16 + fq*4 + r
    const int b = bh >> 4, h = bh & 15;
    const float inv = 1.0f / l_run;
    #pragma unroll
    for (int df = 0; df < 4; ++df)
        #pragma unroll
        for (int r = 0; r < 4; ++r) {
            const int d = df*16 + fq*4 + r;
            attn_out[((size_t)(b*N_ + ql))*E_ + h*64 + d] = f2bfu(o[df][r] * inv);
        }
}

// ---------------------------------------------------------------------------
// Kernel 3: out = attn @ Wo^T + bo (all-bf16 staging, 2-phase prefetch,
// XCD-locality grid: m fastest).
// ---------------------------------------------------------------------------
__global__ __launch_bounds__(256) void out_mfma_kernel(
    const unsigned short* __restrict__ A, const unsigned short* __restrict__ Wobf,
    const float* __restrict__ bo, float* __restrict__ out)
{
    const int m0 = blockIdx.x * 128;
    const int n0 = blockIdx.y * 128;
    __shared__ unsigned short As[128][72];
    __shared__ unsigned short Bs[128][72];
    const int t = threadIdx.x;
    const int lane = t & 63;
    const int w = t >> 6, wr = w >> 1, wc = w & 1;
    const int fr = lane & 15, fq = lane >> 4;
    const int srow = t >> 1, scol = (t & 1) * 32;
    f32x4 acc[4][4] = {};

    const unsigned short* arow = A + (size_t)(m0 + srow) * E_ + scol;
    const unsigned short* brow = Wobf + (size_t)(n0 + srow) * E_ + scol;

    u16x8 a8[4], b8[4];
    #pragma unroll
    for (int i = 0; i < 4; ++i) a8[i] = reinterpret_cast<const u16x8*>(arow)[i];
    #pragma unroll
    for (int i = 0; i < 4; ++i) b8[i] = reinterpret_cast<const u16x8*>(brow)[i];

    for (int k0 = 0; k0 < E_; k0 += 64) {
        __syncthreads();
        #pragma unroll
        for (int j = 0; j < 4; ++j) {
            *reinterpret_cast<u16x8*>(&As[srow][scol + 8*j]) = a8[j];
            *reinterpret_cast<u16x8*>(&Bs[srow][scol + 8*j]) = b8[j];
        }
        __syncthreads();
        if (k0 + 64 < E_) {
            #pragma unroll
            for (int i = 0; i < 4; ++i)
                a8[i] = reinterpret_cast<const u16x8*>(arow + k0 + 64)[i];
            #pragma unroll
            for (int i = 0; i < 4; ++i)
                b8[i] = reinterpret_cast<const u16x8*>(brow + k0 + 64)[i];
        }
        #pragma unroll
        for (int ks = 0; ks < 2; ++ks) {
            bf16x8 af[4], bfv[4];
            #pragma unroll
            for (int mf = 0; mf < 4; ++mf)
                af[mf] = *reinterpret_cast<const bf16x8*>(&As[wr*64 + mf*16 + fr][ks*32 + fq*8]);
            #pragma unroll
            for (int nf = 0; nf < 4; ++nf)
                bfv[nf] = *reinterpret_cast<const bf16x8*>(&Bs[wc*64 + nf*16 + fr][ks*32 + fq*8]);
            #pragma unroll
            for (int mf = 0; mf < 4; ++mf)
                #pragma unroll
                for (int nf = 0; nf < 4; ++nf)
                    acc[mf][nf] = MFMA16(af[mf], bfv[nf], acc[mf][nf]);
        }
    }

    #pragma unroll
    for (int mf = 0; mf < 4; ++mf) {
        #pragma unroll
        for (int r = 0; r < 4; ++r) {
            const int m = m0 + wr*64 + mf*16 + fq*4 + r;
            #pragma unroll
            for (int nf = 0; nf < 4; ++nf) {
                const int n = n0 + wc*64 + nf*16 + fr;
                out[(size_t)m * E_ + n] = acc[mf][nf][r] + bo[n];
            }
        }
    }
}

extern "C" void kernel_launch(void* const* d_in, const int* in_sizes, int n_in,
                              void* d_out, int out_size, void* d_ws, size_t ws_size,
                              hipStream_t stream) {
    const float* x  = (const float*)d_in[0];
    // d_in[1] = mask (causal tril, applied analytically)
    const float* Wq = (const float*)d_in[2];
    const float* Wk = (const float*)d_in[3];
    const float* Wv = (const float*)d_in[4];
    const float* Wo = (const float*)d_in[5];
    const float* bo = (const float*)d_in[6];
    float* out = (float*)d_out;

    unsigned short* ws = (unsigned short*)d_ws;
    const size_t need_main = 5 * RSZ * sizeof(unsigned short);   // 40 MB

    if (ws_size >= need_main) {
        unsigned short* xbf  = ws;
        unsigned short* wbf  = ws + RSZ;
        unsigned short* qkvq = ws + 2 * RSZ;          // Q,K,Vt contiguous
        unsigned short* attn_ws = ws;                 // over xbf (dead)
        unsigned short* wobf = wbf + 3 * (size_t)E_ * E_;

        fconv_all_kernel<<<4096, 256, 0, stream>>>(x, Wq, Wk, Wv, Wo, xbf, wbf);

        dim3 g1(M_ / 128, E_ / 128, 3);               // m fastest: XCD locality
        qkv_bf_kernel<<<g1, 256, 0, stream>>>(xbf, wbf, qkvq);

        dim3 g2(B_ * H_, 16);                         // bh fastest: XCD locality
        attn_mfma_kernel<<<g2, 512, 0, stream>>>(qkvq, attn_ws);

        dim3 g3(M_ / 128, E_ / 128);
        out_mfma_kernel<<<g3, 256, 0, stream>>>(attn_ws, wobf, bo, out);
    } else {
        unsigned short* wbf = ws;
        unsigned short* qkvq = ws + RSZ;
        unsigned short* attn_ws = ws;
        unsigned short* wobf = ws + RSZ;

        const int cgrid = E_ * E_ / (256 * 8);
        fconv_kernel<<<cgrid, 256, 0, stream>>>(Wq, wbf);
        fconv_kernel<<<cgrid, 256, 0, stream>>>(Wk, wbf + (size_t)E_ * E_);
        fconv_kernel<<<cgrid, 256, 0, stream>>>(Wv, wbf + 2 * (size_t)E_ * E_);

        dim3 g1(M_ / 128, E_ / 128, 3);
        qkv_f32_kernel<<<g1, 256, 0, stream>>>(x, wbf, qkvq);

        dim3 g2(B_ * H_, 16);
        attn_mfma_kernel<<<g2, 512, 0, stream>>>(qkvq, attn_ws);

        fconv_kernel<<<cgrid, 256, 0, stream>>>(Wo, wobf);

        dim3 g3(M_ / 128, E_ / 128);
        out_mfma_kernel<<<g3, 256, 0, stream>>>(attn_ws, wobf, bo, out);
    }
}